// Round 4
// baseline (425.217 us; speedup 1.0000x reference)
//
#include <hip/hip_runtime.h>

typedef __bf16 bf16x8 __attribute__((ext_vector_type(8)));
typedef __bf16 bf16x4 __attribute__((ext_vector_type(4)));
typedef short  s16x4  __attribute__((ext_vector_type(4)));
typedef float  f32x4  __attribute__((ext_vector_type(4)));
typedef unsigned int u32x4 __attribute__((ext_vector_type(4)));
typedef unsigned int u32x2 __attribute__((ext_vector_type(2)));
typedef unsigned int u32;
typedef unsigned short u16;

#define DEVI static __device__ __forceinline__

// Bn=2048, L=64, C=256, NH=8, HD=32
static constexpr float KSCALE = 0.17677669529663687f;  // 32^-0.5

DEVI u32 pk2(float a, float b){
  u16 ha = __builtin_bit_cast(u16, (__bf16)a);
  u16 hb = __builtin_bit_cast(u16, (__bf16)b);
  return (u32)ha | ((u32)hb << 16);
}
DEVI u32x2 pkfrag(f32x4 v){ u32x2 o; o[0]=pk2(v[0],v[1]); o[1]=pk2(v[2],v[3]); return o; }
DEVI bf16x8 ld16(const void* p){ return __builtin_bit_cast(bf16x8, *(const u32x4*)p); }
DEVI f32x4 mfma16(bf16x8 a, bf16x8 b, f32x4 c){
  return __builtin_amdgcn_mfma_f32_16x16x32_bf16(a, b, c, 0, 0, 0);
}
// 16x16x16 bf16 MFMA: A/B frag layout is the transpose of the C/D layout ->
// S and PV consume Q/K/V/P straight from accumulator registers.
DEVI f32x4 mfma1616(u32x2 a, u32x2 b, f32x4 c){
#if __has_builtin(__builtin_amdgcn_mfma_f32_16x16x16_bf16)
  return __builtin_amdgcn_mfma_f32_16x16x16_bf16(
      __builtin_bit_cast(bf16x4, a), __builtin_bit_cast(bf16x4, b), c, 0, 0, 0);
#elif __has_builtin(__builtin_amdgcn_mfma_f32_16x16x16bf16_1k)
  return __builtin_amdgcn_mfma_f32_16x16x16bf16_1k(
      __builtin_bit_cast(s16x4, a), __builtin_bit_cast(s16x4, b), c, 0, 0, 0);
#else
  asm("v_mfma_f32_16x16x16_bf16 %0, %1, %2, %0" : "+v"(c) : "v"(a), "v"(b));
  return c;
#endif
}

template<bool BW>
DEVI bf16x8 loadw(const u16* wbp, const float* wfp){
  if constexpr (BW){
    return ld16(wbp);
  } else {
    f32x4 a = *(const f32x4*)wfp;
    f32x4 b = *(const f32x4*)(wfp + 4);
    u32x4 pc; pc[0]=pk2(a[0],a[1]); pc[1]=pk2(a[2],a[3]); pc[2]=pk2(b[0],b[1]); pc[3]=pk2(b[2],b[3]);
    return __builtin_bit_cast(bf16x8, pc);
  }
}

// Permuted weight layout: frag block (M, R, kk) is 1KB contiguous, lane-major:
//   dst[(((M*16+R)*8+kk)*64 + l)*8 + e] = W_M[R*16 + (l&15)][kk*32 + (l>>4)*8 + e]
__global__ void prep_w(const float* __restrict__ qw, const float* __restrict__ kw,
                       const float* __restrict__ vw, const float* __restrict__ pw,
                       u16* __restrict__ dst){
  int blk = blockIdx.x;            // 512 blocks: M(2b) R(4b) kk(3b)
  int l   = threadIdx.x;           // 64
  int M = blk >> 7, R = (blk >> 3) & 15, kk = blk & 7;
  const float* W = (M==0) ? qw : (M==1) ? kw : (M==2) ? vw : pw;
  const float* src = W + (R*16 + (l&15))*256 + kk*32 + (l>>4)*8;
  f32x4 a  = *(const f32x4*)src;
  f32x4 b2 = *(const f32x4*)(src + 4);
  u32x4 pc; pc[0]=pk2(a[0],a[1]); pc[1]=pk2(a[2],a[3]); pc[2]=pk2(b2[0],b2[1]); pc[3]=pk2(b2[2],b2[3]);
  *(u32x4*)(dst + (size_t)blk*512 + l*8) = pc;
}

DEVI const u16* wfrag(const u16* wb, int M, int R, int kk, int l){
  return wb + ((((M<<4) + R)<<3) + kk)*512 + l*8;
}

DEVI void stw(char* T, int t, int j, f32x4 v){   // pack f32x4 -> bf16x4, swizzled store
  int idx = t + 256*j;
  int row = idx >> 6;
  int c0  = (idx & 63) * 4;
  u32x2 o; o[0] = pk2(v[0], v[1]); o[1] = pk2(v[2], v[3]);
  *(u32x2*)(T + row*512 + ((u32)(c0*2) ^ ((u32)(row&7) << 4))) = o;
}

// One block per batch item. 256 threads = 4 waves; wave w owns heads {2w,2w+1}.
// Single 32KB LDS tile T, time-shared: Y -> X -> Y1 -> Y(again) -> f32 out-stage.
// Residual folded into proj by linearity: out = Y1@Wp^T + Y@Wp^T + b.
template<bool BW>
__global__ __launch_bounds__(256, 3)
void fused_ca(const float* __restrict__ x, const float* __restrict__ y,
              const u16* __restrict__ wb,
              const float* __restrict__ qwf, const float* __restrict__ kwf,
              const float* __restrict__ vwf, const float* __restrict__ pwf,
              const float* __restrict__ qb, const float* __restrict__ kb,
              const float* __restrict__ vb, const float* __restrict__ pb,
              float* __restrict__ out)
{
  extern __shared__ char smem[];
  char* T = smem;                       // 32KB
  const int b  = blockIdx.x;
  const int t  = threadIdx.x;
  const int w  = t >> 6;
  const int l  = t & 63;
  const int lo = l & 15;
  const int g  = l >> 4;
  const u32 swr = (u32)(lo & 7) << 4;

  const float* yb = y + (size_t)b * 16384;
  const float* xb = x + (size_t)b * 16384;

  // ---- stage Y -> T ----
  {
    f32x4 yr[8], yr2[8];
    #pragma unroll
    for (int j = 0; j < 8; ++j){
      int idx = t + 256*j;
      yr[j] = *(const f32x4*)(yb + (idx>>6)*256 + (idx&63)*4);
    }
    #pragma unroll
    for (int j = 0; j < 8; ++j){
      int idx = t + 256*(j+8);
      yr2[j] = *(const f32x4*)(yb + (idx>>6)*256 + (idx&63)*4);
    }
    #pragma unroll
    for (int j = 0; j < 8; ++j) stw(T, t, j, yr[j]);
    #pragma unroll
    for (int j = 0; j < 8; ++j) stw(T, t, j+8, yr2[j]);
  }
  // issue X batch 0 early (cold HBM latency hides under Q-GEMM)
  f32x4 xr[8];
  #pragma unroll
  for (int j = 0; j < 8; ++j){
    int idx = t + 256*j;
    xr[j] = *(const f32x4*)(xb + (idx>>6)*256 + (idx&63)*4);
  }
  __syncthreads();   // Y readable

  // ---- Q-GEMMs (both heads) ----
  u32x2 aqpk[2][8];    // [hl][m*4+n]
  f32x4 xr2[8];
  #pragma unroll
  for (int hl = 0; hl < 2; ++hl){
    const int cb = w*64 + hl*32;
    const int Rb = w*4 + hl*2;
    f32x4 aq[2][4] = {};
    #pragma unroll
    for (int kk = 0; kk < 8; ++kk){
      bf16x8 A[2], Bf[4];
      #pragma unroll
      for (int m = 0; m < 2; ++m){
        int off = (cb + 16*m + lo)*256 + kk*32 + 8*g;
        A[m] = loadw<BW>(wfrag(wb, 0, Rb + m, kk, l), qwf + off);
      }
      #pragma unroll
      for (int n = 0; n < 4; ++n)
        Bf[n] = ld16(T + (16*n+lo)*512 + ((u32)(kk*64 + 16*g) ^ swr));
      #pragma unroll
      for (int m = 0; m < 2; ++m)
        #pragma unroll
        for (int n = 0; n < 4; ++n)
          aq[m][n] = mfma16(A[m], Bf[n], aq[m][n]);
    }
    #pragma unroll
    for (int m = 0; m < 2; ++m){
      f32x4 bias = *(const f32x4*)(qb + cb + 16*m + 4*g);
      #pragma unroll
      for (int n = 0; n < 4; ++n){
        f32x4 v;
        #pragma unroll
        for (int r = 0; r < 4; ++r) v[r] = (aq[m][n][r] + bias[r]) * KSCALE;
        aqpk[hl][m*4+n] = pkfrag(v);
      }
    }
    if (hl == 0){
      #pragma unroll
      for (int j = 0; j < 8; ++j){
        int idx = t + 256*(j+8);
        xr2[j] = *(const f32x4*)(xb + (idx>>6)*256 + (idx&63)*4);
      }
    }
  }
  __syncthreads();   // all Q-GEMM reads of T(Y) done

  // ---- stage X -> T ----
  #pragma unroll
  for (int j = 0; j < 8; ++j) stw(T, t, j, xr[j]);
  #pragma unroll
  for (int j = 0; j < 8; ++j) stw(T, t, j+8, xr2[j]);
  __syncthreads();   // X readable

  // ---- K/V GEMM, both heads; K,V stay packed in regs ----
  u32x2 akpk[2][8], avpk[2][8];   // [hl][m*4+f], [hl][f*2+n]
  #pragma unroll
  for (int hl = 0; hl < 2; ++hl){
    const int cb = w*64 + hl*32;
    const int Rb = w*4 + hl*2;
    f32x4 ak[2][4] = {};
    f32x4 av[4][2] = {};
    #pragma unroll
    for (int kk = 0; kk < 8; ++kk){
      bf16x8 WA[2], WB2[2], XF[4];
      #pragma unroll
      for (int m = 0; m < 2; ++m){
        int off = (cb + 16*m + lo)*256 + kk*32 + 8*g;
        WA[m] = loadw<BW>(wfrag(wb, 1, Rb + m, kk, l), kwf + off);
      }
      #pragma unroll
      for (int n = 0; n < 2; ++n){
        int off = (cb + 16*n + lo)*256 + kk*32 + 8*g;
        WB2[n] = loadw<BW>(wfrag(wb, 2, Rb + n, kk, l), vwf + off);
      }
      #pragma unroll
      for (int f = 0; f < 4; ++f)
        XF[f] = ld16(T + (16*f+lo)*512 + ((u32)(kk*64 + 16*g) ^ swr));
      #pragma unroll
      for (int f = 0; f < 4; ++f){
        #pragma unroll
        for (int m = 0; m < 2; ++m)
          ak[m][f] = mfma16(WA[m], XF[f], ak[m][f]);
        #pragma unroll
        for (int n = 0; n < 2; ++n)
          av[f][n] = mfma16(XF[f], WB2[n], av[f][n]);
      }
    }
    #pragma unroll
    for (int m = 0; m < 2; ++m){
      f32x4 bias = *(const f32x4*)(kb + cb + 16*m + 4*g);
      #pragma unroll
      for (int f = 0; f < 4; ++f){
        f32x4 v;
        #pragma unroll
        for (int r = 0; r < 4; ++r) v[r] = ak[m][f][r] + bias[r];
        akpk[hl][m*4+f] = pkfrag(v);
      }
    }
    #pragma unroll
    for (int n = 0; n < 2; ++n){
      float bias = vb[cb + 16*n + lo];
      #pragma unroll
      for (int f = 0; f < 4; ++f){
        f32x4 v;
        #pragma unroll
        for (int r = 0; r < 4; ++r) v[r] = av[f][n][r] + bias;
        avpk[hl][f*2+n] = pkfrag(v);
      }
    }
  }
  __syncthreads();   // all K/V reads of T(X) done; T free for Y1

  // ---- attention per head; write y1 (bf16) into T ----
  #pragma unroll
  for (int hl = 0; hl < 2; ++hl){
    const int cb = w*64 + hl*32;
    f32x4 y1h[2][4] = {};   // [md][n]
    #pragma unroll
    for (int n = 0; n < 4; ++n){
      f32x4 s4[4];
      #pragma unroll
      for (int f = 0; f < 4; ++f){
        f32x4 acc = {};
        acc = mfma1616(akpk[hl][0*4+f], aqpk[hl][0*4+n], acc);
        acc = mfma1616(akpk[hl][1*4+f], aqpk[hl][1*4+n], acc);
        s4[f] = acc;
      }
      float mx = s4[0][0];
      #pragma unroll
      for (int f = 0; f < 4; ++f)
        #pragma unroll
        for (int r = 0; r < 4; ++r)
          mx = fmaxf(mx, s4[f][r]);
      mx = fmaxf(mx, __shfl_xor(mx, 16));
      mx = fmaxf(mx, __shfl_xor(mx, 32));
      float sum = 0.f;
      #pragma unroll
      for (int f = 0; f < 4; ++f)
        #pragma unroll
        for (int r = 0; r < 4; ++r){
          float e = __expf(s4[f][r] - mx);
          s4[f][r] = e; sum += e;
        }
      sum += __shfl_xor(sum, 16);
      sum += __shfl_xor(sum, 32);
      float rin = 1.0f / (sum + 1.0f);
      u32x2 spk[4];
      #pragma unroll
      for (int f = 0; f < 4; ++f){
        f32x4 v;
        #pragma unroll
        for (int r = 0; r < 4; ++r) v[r] = s4[f][r] * rin;
        spk[f] = pkfrag(v);
      }
      #pragma unroll
      for (int md = 0; md < 2; ++md)
        #pragma unroll
        for (int f = 0; f < 4; ++f)
          y1h[md][n] = mfma1616(avpk[hl][f*2+md], spk[f], y1h[md][n]);
    }
    // write y1 tile (wave-private cols)
    #pragma unroll
    for (int md = 0; md < 2; ++md)
      #pragma unroll
      for (int n = 0; n < 4; ++n){
        int c0 = cb + 16*md + 4*g;
        *(u32x2*)(T + (16*n+lo)*512 + ((u32)(c0*2) ^ swr)) = pkfrag(y1h[md][n]);
      }
  }
  __syncthreads();   // Y1 readable

  // ---- proj pass A: ap = Y1 @ pw^T ----
  f32x4 ap[4][4] = {};
  f32x4 yra[8];
  #pragma unroll
  for (int j = 0; j < 8; ++j){   // re-issue Y loads (L3-warm) under pass A
    int idx = t + 256*j;
    yra[j] = *(const f32x4*)(yb + (idx>>6)*256 + (idx&63)*4);
  }
  #pragma unroll
  for (int kk = 0; kk < 8; ++kk){
    bf16x8 Af[4], Bp[4];
    #pragma unroll
    for (int m = 0; m < 4; ++m)
      Af[m] = ld16(T + (16*m+lo)*512 + ((u32)(kk*64 + 16*g) ^ swr));
    #pragma unroll
    for (int n = 0; n < 4; ++n){
      int off = (w*64 + 16*n + lo)*256 + kk*32 + 8*g;
      Bp[n] = loadw<BW>(wfrag(wb, 3, w*4 + n, kk, l), pwf + off);
    }
    #pragma unroll
    for (int m = 0; m < 4; ++m)
      #pragma unroll
      for (int n = 0; n < 4; ++n)
        ap[m][n] = mfma16(Af[m], Bp[n], ap[m][n]);
  }
  f32x4 yrb[8];
  #pragma unroll
  for (int j = 0; j < 8; ++j){
    int idx = t + 256*(j+8);
    yrb[j] = *(const f32x4*)(yb + (idx>>6)*256 + (idx&63)*4);
  }
  __syncthreads();   // pass-A reads of T(Y1) done

  // ---- re-stage Y -> T ----
  #pragma unroll
  for (int j = 0; j < 8; ++j) stw(T, t, j, yra[j]);
  #pragma unroll
  for (int j = 0; j < 8; ++j) stw(T, t, j+8, yrb[j]);
  __syncthreads();   // Y readable

  // ---- proj pass B: ap += Y @ pw^T ----
  #pragma unroll
  for (int kk = 0; kk < 8; ++kk){
    bf16x8 Af[4], Bp[4];
    #pragma unroll
    for (int m = 0; m < 4; ++m)
      Af[m] = ld16(T + (16*m+lo)*512 + ((u32)(kk*64 + 16*g) ^ swr));
    #pragma unroll
    for (int n = 0; n < 4; ++n){
      int off = (w*64 + 16*n + lo)*256 + kk*32 + 8*g;
      Bp[n] = loadw<BW>(wfrag(wb, 3, w*4 + n, kk, l), pwf + off);
    }
    #pragma unroll
    for (int m = 0; m < 4; ++m)
      #pragma unroll
      for (int n = 0; n < 4; ++n)
        ap[m][n] = mfma16(Af[m], Bp[n], ap[m][n]);
  }

  float pbv[4];
  #pragma unroll
  for (int n = 0; n < 4; ++n) pbv[n] = pb[w*64 + 16*n + lo];
  #pragma unroll
  for (int m = 0; m < 4; ++m)
    #pragma unroll
    for (int n = 0; n < 4; ++n)
      #pragma unroll
      for (int r = 0; r < 4; ++r)
        ap[m][n][r] += pbv[n];

  // ---- coalesced store via LDS transpose (T reused as [32][256] f32) ----
  float* ob = out + (size_t)b * 16384;
  #pragma unroll
  for (int half = 0; half < 2; ++half){
    __syncthreads();
    #pragma unroll
    for (int mm = 0; mm < 2; ++mm)
      #pragma unroll
      for (int n = 0; n < 4; ++n){
        int col = w*64 + 16*n + lo;
        #pragma unroll
        for (int r = 0; r < 4; ++r){
          int row = mm*16 + 4*g + r;                      // 0..31
          u32 byteoff = ((u32)(row*1024 + col*4)) ^ ((u32)(row & 4) << 4);
          *(float*)(T + byteoff) = ap[half*2 + mm][n][r];
        }
      }
    __syncthreads();
    #pragma unroll
    for (int i = 0; i < 8; ++i){
      int id  = i*256 + t;
      int row = id >> 6;                                  // 0..31
      int cc  = id & 63;
      u32 byteoff = (u32)(row*1024) + ((u32)(cc ^ (row & 4)) << 4);
      f32x4 v = *(const f32x4*)(T + byteoff);
      *(f32x4*)(ob + (half*32 + row)*256 + cc*4) = v;
    }
  }
}

extern "C" void kernel_launch(void* const* d_in, const int* in_sizes, int n_in,
                              void* d_out, int out_size, void* d_ws, size_t ws_size,
                              hipStream_t stream) {
  (void)n_in; (void)out_size;
  const float* x  = (const float*)d_in[0];
  const float* y  = (const float*)d_in[1];
  // d_in[2] (z) is unused by the reference forward
  const float* qw = (const float*)d_in[3];
  const float* qb = (const float*)d_in[4];
  const float* kw = (const float*)d_in[5];
  const float* kb = (const float*)d_in[6];
  const float* vw = (const float*)d_in[7];
  const float* vb = (const float*)d_in[8];
  const float* pw = (const float*)d_in[9];
  const float* pb = (const float*)d_in[10];
  float* out = (float*)d_out;
  const int Bn = in_sizes[0] / 16384;   // 2048

  const bool useWs = ws_size >= (size_t)524288;
  if (useWs){
    u16* wsb = (u16*)d_ws;
    prep_w<<<512, 64, 0, stream>>>(qw, kw, vw, pw, wsb);
    fused_ca<true><<<Bn, 256, 32768, stream>>>(x, y, wsb, qw, kw, vw, pw,
                                               qb, kb, vb, pb, out);
  } else {
    fused_ca<false><<<Bn, 256, 32768, stream>>>(x, y, (const u16*)d_ws, qw, kw, vw, pw,
                                                qb, kb, vb, pb, out);
  }
}

// Round 5
// 410.872 us; speedup vs baseline: 1.0349x; 1.0349x over previous
//
#include <hip/hip_runtime.h>

typedef __bf16 bf16x8 __attribute__((ext_vector_type(8)));
typedef __bf16 bf16x4 __attribute__((ext_vector_type(4)));
typedef short  s16x4  __attribute__((ext_vector_type(4)));
typedef float  f32x4  __attribute__((ext_vector_type(4)));
typedef unsigned int u32x4 __attribute__((ext_vector_type(4)));
typedef unsigned int u32x2 __attribute__((ext_vector_type(2)));
typedef unsigned int u32;
typedef unsigned short u16;

#define DEVI static __device__ __forceinline__

// Bn=2048, L=64, C=256, NH=8, HD=32
static constexpr float KSCALE = 0.17677669529663687f;  // 32^-0.5

DEVI u32 pk2(float a, float b){
  u16 ha = __builtin_bit_cast(u16, (__bf16)a);
  u16 hb = __builtin_bit_cast(u16, (__bf16)b);
  return (u32)ha | ((u32)hb << 16);
}
DEVI float bfl(u32 bits16){            // low 16 bits hold a bf16
  union { u32 i; float f; } v; v.i = bits16 << 16; return v.f;
}
DEVI u32x2 pkfrag(f32x4 v){ u32x2 o; o[0]=pk2(v[0],v[1]); o[1]=pk2(v[2],v[3]); return o; }
DEVI bf16x8 ld16(const void* p){ return __builtin_bit_cast(bf16x8, *(const u32x4*)p); }
DEVI f32x4 mfma16(bf16x8 a, bf16x8 b, f32x4 c){
  return __builtin_amdgcn_mfma_f32_16x16x32_bf16(a, b, c, 0, 0, 0);
}
// 16x16x16 bf16 MFMA: A/B frag layout is the transpose of the C/D layout ->
// S and PV consume Q/K/V/P straight from accumulator registers.
DEVI f32x4 mfma1616(u32x2 a, u32x2 b, f32x4 c){
#if __has_builtin(__builtin_amdgcn_mfma_f32_16x16x16_bf16)
  return __builtin_amdgcn_mfma_f32_16x16x16_bf16(
      __builtin_bit_cast(bf16x4, a), __builtin_bit_cast(bf16x4, b), c, 0, 0, 0);
#elif __has_builtin(__builtin_amdgcn_mfma_f32_16x16x16bf16_1k)
  return __builtin_amdgcn_mfma_f32_16x16x16bf16_1k(
      __builtin_bit_cast(s16x4, a), __builtin_bit_cast(s16x4, b), c, 0, 0, 0);
#else
  asm("v_mfma_f32_16x16x16_bf16 %0, %1, %2, %0" : "+v"(c) : "v"(a), "v"(b));
  return c;
#endif
}

template<bool BW>
DEVI bf16x8 loadw(const u16* wbp, const float* wfp){
  if constexpr (BW){
    return ld16(wbp);
  } else {
    f32x4 a = *(const f32x4*)wfp;
    f32x4 b = *(const f32x4*)(wfp + 4);
    u32x4 pc; pc[0]=pk2(a[0],a[1]); pc[1]=pk2(a[2],a[3]); pc[2]=pk2(b[0],b[1]); pc[3]=pk2(b[2],b[3]);
    return __builtin_bit_cast(bf16x8, pc);
  }
}

// Permuted weight layout: frag block (M, R, kk) is 1KB contiguous, lane-major:
//   dst[(((M*16+R)*8+kk)*64 + l)*8 + e] = W_M[R*16 + (l&15)][kk*32 + (l>>4)*8 + e]
__global__ void prep_w(const float* __restrict__ qw, const float* __restrict__ kw,
                       const float* __restrict__ vw, const float* __restrict__ pw,
                       u16* __restrict__ dst){
  int blk = blockIdx.x;            // 512 blocks: M(2b) R(4b) kk(3b)
  int l   = threadIdx.x;           // 64
  int M = blk >> 7, R = (blk >> 3) & 15, kk = blk & 7;
  const float* W = (M==0) ? qw : (M==1) ? kw : (M==2) ? vw : pw;
  const float* src = W + (R*16 + (l&15))*256 + kk*32 + (l>>4)*8;
  f32x4 a  = *(const f32x4*)src;
  f32x4 b2 = *(const f32x4*)(src + 4);
  u32x4 pc; pc[0]=pk2(a[0],a[1]); pc[1]=pk2(a[2],a[3]); pc[2]=pk2(b2[0],b2[1]); pc[3]=pk2(b2[2],b2[3]);
  *(u32x4*)(dst + (size_t)blk*512 + l*8) = pc;
}

DEVI const u16* wfrag(const u16* wb, int M, int R, int kk, int l){
  return wb + ((((M<<4) + R)<<3) + kk)*512 + l*8;
}

// One block per batch item. 256 threads = 4 waves; wave w owns heads {2w,2w+1}.
// LDS 32KB: r1 = Y / (Y+Y1) bf16 [64][256] pitch 512B swizzled; f32 out-stage at end.
// X is never staged: K/V-GEMM B-fragments are 32B/lane contiguous global reads.
// Q/K/V/P never touch LDS (16x16x16 MFMA register-fragment trick).
template<bool BW>
__global__ __launch_bounds__(256, 3)
void fused_ca(const float* __restrict__ x, const float* __restrict__ y,
              const u16* __restrict__ wb,
              const float* __restrict__ qwf, const float* __restrict__ kwf,
              const float* __restrict__ vwf, const float* __restrict__ pwf,
              const float* __restrict__ qb, const float* __restrict__ kb,
              const float* __restrict__ vb, const float* __restrict__ pb,
              float* __restrict__ out)
{
  extern __shared__ char smem[];
  char* r1 = smem;                      // 32KB
  const int b  = blockIdx.x;
  const int t  = threadIdx.x;
  const int w  = t >> 6;
  const int l  = t & 63;
  const int lo = l & 15;
  const int g  = l >> 4;
  const u32 swr = (u32)(lo & 7) << 4;

  const float* yb = y + (size_t)b * 16384;
  const float* xb = x + (size_t)b * 16384;

  // ---- stage Y -> r1 (bf16, swizzled) ----
  #pragma unroll
  for (int j = 0; j < 16; ++j){
    int idx = t + 256*j;
    int row = idx >> 6;
    int c0  = (idx & 63) * 4;
    f32x4 v = *(const f32x4*)(yb + row*256 + c0);
    u32x2 o; o[0] = pk2(v[0], v[1]); o[1] = pk2(v[2], v[3]);
    *(u32x2*)(r1 + row*512 + ((u32)(c0*2) ^ ((u32)(row&7) << 4))) = o;
  }
  __syncthreads();   // Y readable

  // ---- Q-GEMMs (both heads) ----
  u32x2 aqpk[2][8];    // [hl][m*4+n]
  #pragma unroll
  for (int hl = 0; hl < 2; ++hl){
    const int cb = w*64 + hl*32;
    const int Rb = w*4 + hl*2;
    f32x4 aq[2][4] = {};
    #pragma unroll
    for (int kk = 0; kk < 8; ++kk){
      bf16x8 A[2], Bf[4];
      #pragma unroll
      for (int m = 0; m < 2; ++m){
        int off = (cb + 16*m + lo)*256 + kk*32 + 8*g;
        A[m] = loadw<BW>(wfrag(wb, 0, Rb + m, kk, l), qwf + off);
      }
      #pragma unroll
      for (int n = 0; n < 4; ++n)
        Bf[n] = ld16(r1 + (16*n+lo)*512 + ((u32)(kk*64 + 16*g) ^ swr));
      #pragma unroll
      for (int m = 0; m < 2; ++m)
        #pragma unroll
        for (int n = 0; n < 4; ++n)
          aq[m][n] = mfma16(A[m], Bf[n], aq[m][n]);
    }
    #pragma unroll
    for (int m = 0; m < 2; ++m){
      f32x4 bias = *(const f32x4*)(qb + cb + 16*m + 4*g);
      #pragma unroll
      for (int n = 0; n < 4; ++n){
        f32x4 v;
        #pragma unroll
        for (int r = 0; r < 4; ++r) v[r] = (aq[m][n][r] + bias[r]) * KSCALE;
        aqpk[hl][m*4+n] = pkfrag(v);
      }
    }
  }
  __syncthreads();   // all Q-GEMM reads of r1(Y) done; r1 writes (residual) now safe

  // ---- per head: K/V GEMM (X direct from global) -> attention -> residual ----
  #pragma unroll
  for (int hl = 0; hl < 2; ++hl){
    const int cb = w*64 + hl*32;
    const int Rb = w*4 + hl*2;

    f32x4 ak[2][4] = {};   // K^T tiles [m][f]
    f32x4 av[4][2] = {};   // V tiles [f][n]
    #pragma unroll
    for (int kk = 0; kk < 8; ++kk){
      bf16x8 WA[2], WB2[2], XF[4];
      #pragma unroll
      for (int m = 0; m < 2; ++m){
        int off = (cb + 16*m + lo)*256 + kk*32 + 8*g;
        WA[m] = loadw<BW>(wfrag(wb, 1, Rb + m, kk, l), kwf + off);
      }
      #pragma unroll
      for (int n = 0; n < 2; ++n){
        int off = (cb + 16*n + lo)*256 + kk*32 + 8*g;
        WB2[n] = loadw<BW>(wfrag(wb, 2, Rb + n, kk, l), vwf + off);
      }
      #pragma unroll
      for (int f = 0; f < 4; ++f){
        const float* px = xb + (16*f + lo)*256 + kk*32 + 8*g;
        f32x4 u0 = *(const f32x4*)px;
        f32x4 u1 = *(const f32x4*)(px + 4);
        u32x4 pc; pc[0]=pk2(u0[0],u0[1]); pc[1]=pk2(u0[2],u0[3]);
                  pc[2]=pk2(u1[0],u1[1]); pc[3]=pk2(u1[2],u1[3]);
        XF[f] = __builtin_bit_cast(bf16x8, pc);
      }
      #pragma unroll
      for (int f = 0; f < 4; ++f){
        #pragma unroll
        for (int m = 0; m < 2; ++m)
          ak[m][f] = mfma16(WA[m], XF[f], ak[m][f]);
        #pragma unroll
        for (int n = 0; n < 2; ++n)
          av[f][n] = mfma16(XF[f], WB2[n], av[f][n]);
      }
    }
    // pack K, V into A/B fragments (in-lane only)
    u32x2 akpk[8], avpk[8];   // [m*4+f], [f*2+n]
    #pragma unroll
    for (int m = 0; m < 2; ++m){
      f32x4 bias = *(const f32x4*)(kb + cb + 16*m + 4*g);
      #pragma unroll
      for (int f = 0; f < 4; ++f){
        f32x4 v;
        #pragma unroll
        for (int r = 0; r < 4; ++r) v[r] = ak[m][f][r] + bias[r];
        akpk[m*4+f] = pkfrag(v);
      }
    }
    #pragma unroll
    for (int n = 0; n < 2; ++n){
      float bias = vb[cb + 16*n + lo];
      #pragma unroll
      for (int f = 0; f < 4; ++f){
        f32x4 v;
        #pragma unroll
        for (int r = 0; r < 4; ++r) v[r] = av[f][n][r] + bias;
        avpk[f*2+n] = pkfrag(v);
      }
    }

    // ---- attention: per q-tile n, S (16x16x16) -> softmax+1 -> PV ----
    f32x4 y1h[2][4] = {};   // [md][n] : Y1^T tiles
    #pragma unroll
    for (int n = 0; n < 4; ++n){
      f32x4 s4[4];
      #pragma unroll
      for (int f = 0; f < 4; ++f){
        f32x4 acc = {};
        acc = mfma1616(akpk[0*4+f], aqpk[hl][0*4+n], acc);
        acc = mfma1616(akpk[1*4+f], aqpk[hl][1*4+n], acc);
        s4[f] = acc;
      }
      float mx = s4[0][0];
      #pragma unroll
      for (int f = 0; f < 4; ++f)
        #pragma unroll
        for (int r = 0; r < 4; ++r)
          mx = fmaxf(mx, s4[f][r]);
      mx = fmaxf(mx, __shfl_xor(mx, 16));
      mx = fmaxf(mx, __shfl_xor(mx, 32));
      float sum = 0.f;
      #pragma unroll
      for (int f = 0; f < 4; ++f)
        #pragma unroll
        for (int r = 0; r < 4; ++r){
          float e = __expf(s4[f][r] - mx);
          s4[f][r] = e; sum += e;
        }
      sum += __shfl_xor(sum, 16);
      sum += __shfl_xor(sum, 32);
      float rin = 1.0f / (sum + 1.0f);
      u32x2 spk[4];
      #pragma unroll
      for (int f = 0; f < 4; ++f){
        f32x4 v;
        #pragma unroll
        for (int r = 0; r < 4; ++r) v[r] = s4[f][r] * rin;
        spk[f] = pkfrag(v);
      }
      #pragma unroll
      for (int md = 0; md < 2; ++md)
        #pragma unroll
        for (int f = 0; f < 4; ++f)
          y1h[md][n] = mfma1616(avpk[f*2+md], spk[f], y1h[md][n]);
    }

    // ---- residual: r1 += y1 (wave-private cols) ----
    #pragma unroll
    for (int md = 0; md < 2; ++md)
      #pragma unroll
      for (int n = 0; n < 4; ++n){
        int c0 = cb + 16*md + 4*g;
        char* p = r1 + (16*n+lo)*512 + ((u32)(c0*2) ^ swr);
        u32x2 old = *(const u32x2*)p;
        f32x4 a = y1h[md][n];
        float o0 = bfl(old[0] & 0xffffu) + a[0];
        float o1 = bfl(old[0] >> 16)     + a[1];
        float o2 = bfl(old[1] & 0xffffu) + a[2];
        float o3 = bfl(old[1] >> 16)     + a[3];
        u32x2 nw; nw[0] = pk2(o0, o1); nw[1] = pk2(o2, o3);
        *(u32x2*)p = nw;
      }
  } // heads

  __syncthreads();   // residual writes visible to all

  // ---- proj: out = r1 @ proj_w^T + proj_b ----
  f32x4 ap[4][4] = {};
  #pragma unroll
  for (int kk = 0; kk < 8; ++kk){
    bf16x8 Af[4], Bp[4];
    #pragma unroll
    for (int m = 0; m < 4; ++m)
      Af[m] = ld16(r1 + (16*m+lo)*512 + ((u32)(kk*64 + 16*g) ^ swr));
    #pragma unroll
    for (int n = 0; n < 4; ++n){
      int off = (w*64 + 16*n + lo)*256 + kk*32 + 8*g;
      Bp[n] = loadw<BW>(wfrag(wb, 3, w*4 + n, kk, l), pwf + off);
    }
    #pragma unroll
    for (int m = 0; m < 4; ++m)
      #pragma unroll
      for (int n = 0; n < 4; ++n)
        ap[m][n] = mfma16(Af[m], Bp[n], ap[m][n]);
  }

  float pbv[4];
  #pragma unroll
  for (int n = 0; n < 4; ++n) pbv[n] = pb[w*64 + 16*n + lo];
  #pragma unroll
  for (int m = 0; m < 4; ++m)
    #pragma unroll
    for (int n = 0; n < 4; ++n)
      #pragma unroll
      for (int r = 0; r < 4; ++r)
        ap[m][n][r] += pbv[n];

  // ---- coalesced store via LDS transpose (r1 reused as [32][256] f32) ----
  float* ob = out + (size_t)b * 16384;
  #pragma unroll
  for (int half = 0; half < 2; ++half){
    __syncthreads();
    #pragma unroll
    for (int mm = 0; mm < 2; ++mm)
      #pragma unroll
      for (int n = 0; n < 4; ++n){
        int col = w*64 + 16*n + lo;
        #pragma unroll
        for (int r = 0; r < 4; ++r){
          int row = mm*16 + 4*g + r;                      // 0..31
          u32 byteoff = ((u32)(row*1024 + col*4)) ^ ((u32)(row & 4) << 4);
          *(float*)(r1 + byteoff) = ap[half*2 + mm][n][r];
        }
      }
    __syncthreads();
    #pragma unroll
    for (int i = 0; i < 8; ++i){
      int id  = i*256 + t;
      int row = id >> 6;                                  // 0..31
      int cc  = id & 63;
      u32 byteoff = (u32)(row*1024) + ((u32)(cc ^ (row & 4)) << 4);
      f32x4 v = *(const f32x4*)(r1 + byteoff);
      *(f32x4*)(ob + (half*32 + row)*256 + cc*4) = v;
    }
  }
}

extern "C" void kernel_launch(void* const* d_in, const int* in_sizes, int n_in,
                              void* d_out, int out_size, void* d_ws, size_t ws_size,
                              hipStream_t stream) {
  (void)n_in; (void)out_size;
  const float* x  = (const float*)d_in[0];
  const float* y  = (const float*)d_in[1];
  // d_in[2] (z) is unused by the reference forward
  const float* qw = (const float*)d_in[3];
  const float* qb = (const float*)d_in[4];
  const float* kw = (const float*)d_in[5];
  const float* kb = (const float*)d_in[6];
  const float* vw = (const float*)d_in[7];
  const float* vb = (const float*)d_in[8];
  const float* pw = (const float*)d_in[9];
  const float* pb = (const float*)d_in[10];
  float* out = (float*)d_out;
  const int Bn = in_sizes[0] / 16384;   // 2048

  const bool useWs = ws_size >= (size_t)524288;
  if (useWs){
    u16* wsb = (u16*)d_ws;
    prep_w<<<512, 64, 0, stream>>>(qw, kw, vw, pw, wsb);
    fused_ca<true><<<Bn, 256, 32768, stream>>>(x, y, wsb, qw, kw, vw, pw,
                                               qb, kb, vb, pb, out);
  } else {
    fused_ca<false><<<Bn, 256, 32768, stream>>>(x, y, (const u16*)d_ws, qw, kw, vw, pw,
                                                qb, kb, vb, pb, out);
  }
}

// Round 6
// 236.440 us; speedup vs baseline: 1.7984x; 1.7377x over previous
//
#include <hip/hip_runtime.h>

typedef __bf16 bf16x8 __attribute__((ext_vector_type(8)));
typedef __bf16 bf16x4 __attribute__((ext_vector_type(4)));
typedef short  s16x4  __attribute__((ext_vector_type(4)));
typedef float  f32x4  __attribute__((ext_vector_type(4)));
typedef unsigned int u32x4 __attribute__((ext_vector_type(4)));
typedef unsigned int u32x2 __attribute__((ext_vector_type(2)));
typedef unsigned int u32;
typedef unsigned short u16;

#define DEVI static __device__ __forceinline__

// Bn=2048, L=64, C=256, NH=8, HD=32
static constexpr float KSCALE = 0.17677669529663687f;  // 32^-0.5

DEVI u32 pk2(float a, float b){
  u16 ha = __builtin_bit_cast(u16, (__bf16)a);
  u16 hb = __builtin_bit_cast(u16, (__bf16)b);
  return (u32)ha | ((u32)hb << 16);
}
DEVI float bfl(u32 bits16){            // low 16 bits hold a bf16
  union { u32 i; float f; } v; v.i = bits16 << 16; return v.f;
}
DEVI u32x2 pkfrag(f32x4 v){ u32x2 o; o[0]=pk2(v[0],v[1]); o[1]=pk2(v[2],v[3]); return o; }
DEVI bf16x8 ld16(const void* p){ return __builtin_bit_cast(bf16x8, *(const u32x4*)p); }
DEVI f32x4 mfma16(bf16x8 a, bf16x8 b, f32x4 c){
  return __builtin_amdgcn_mfma_f32_16x16x32_bf16(a, b, c, 0, 0, 0);
}
// 16x16x16 bf16 MFMA: A/B frag layout is the transpose of the C/D layout ->
// S and PV consume Q/K/V/P straight from accumulator registers.
DEVI f32x4 mfma1616(u32x2 a, u32x2 b, f32x4 c){
#if __has_builtin(__builtin_amdgcn_mfma_f32_16x16x16_bf16)
  return __builtin_amdgcn_mfma_f32_16x16x16_bf16(
      __builtin_bit_cast(bf16x4, a), __builtin_bit_cast(bf16x4, b), c, 0, 0, 0);
#elif __has_builtin(__builtin_amdgcn_mfma_f32_16x16x16bf16_1k)
  return __builtin_amdgcn_mfma_f32_16x16x16bf16_1k(
      __builtin_bit_cast(s16x4, a), __builtin_bit_cast(s16x4, b), c, 0, 0, 0);
#else
  asm("v_mfma_f32_16x16x16_bf16 %0, %1, %2, %0" : "+v"(c) : "v"(a), "v"(b));
  return c;
#endif
}

template<bool BW>
DEVI bf16x8 loadw(const u16* wbp, const float* wfp){
  if constexpr (BW){
    return ld16(wbp);
  } else {
    f32x4 a = *(const f32x4*)wfp;
    f32x4 b = *(const f32x4*)(wfp + 4);
    u32x4 pc; pc[0]=pk2(a[0],a[1]); pc[1]=pk2(a[2],a[3]); pc[2]=pk2(b[0],b[1]); pc[3]=pk2(b[2],b[3]);
    return __builtin_bit_cast(bf16x8, pc);
  }
}

// Permuted weight layout: frag block (M, R, kk) is 1KB contiguous, lane-major:
//   dst[(((M*16+R)*8+kk)*64 + l)*8 + e] = W_M[R*16 + (l&15)][kk*32 + (l>>4)*8 + e]
__global__ void prep_w(const float* __restrict__ qw, const float* __restrict__ kw,
                       const float* __restrict__ vw, const float* __restrict__ pw,
                       u16* __restrict__ dst){
  int blk = blockIdx.x;            // 512 blocks: M(2b) R(4b) kk(3b)
  int l   = threadIdx.x;           // 64
  int M = blk >> 7, R = (blk >> 3) & 15, kk = blk & 7;
  const float* W = (M==0) ? qw : (M==1) ? kw : (M==2) ? vw : pw;
  const float* src = W + (R*16 + (l&15))*256 + kk*32 + (l>>4)*8;
  f32x4 a  = *(const f32x4*)src;
  f32x4 b2 = *(const f32x4*)(src + 4);
  u32x4 pc; pc[0]=pk2(a[0],a[1]); pc[1]=pk2(a[2],a[3]); pc[2]=pk2(b2[0],b2[1]); pc[3]=pk2(b2[2],b2[3]);
  *(u32x4*)(dst + (size_t)blk*512 + l*8) = pc;
}

DEVI const u16* wfrag(const u16* wb, int M, int R, int kk, int l){
  return wb + ((((M<<4) + R)<<3) + kk)*512 + l*8;
}

DEVI void stw(char* T, int idx, f32x4 v){   // pack f32x4 -> bf16x4, swizzled store
  int row = idx >> 6;
  int c0  = (idx & 63) * 4;
  u32x2 o; o[0] = pk2(v[0], v[1]); o[1] = pk2(v[2], v[3]);
  *(u32x2*)(T + row*512 + ((u32)(c0*2) ^ ((u32)(row&7) << 4))) = o;
}

// One block per batch item. 512 threads = 8 waves; wave w owns head w (cols
// [32w, 32w+32)). LDS 64KB: r1 = Y/(Y+Y1) bf16 [64][256] pitch 512B swizzled;
// Xs = X bf16 same layout. Epilogue reuses all 64KB as [64][256] f32 out-stage.
// Q/K/V/P never touch LDS (16x16x16 register-fragment trick). K-pass and
// V-pass are separate kk-loops to keep peak live regs under the 128 cap.
template<bool BW>
__global__ __launch_bounds__(512, 4)
void fused_ca(const float* __restrict__ x, const float* __restrict__ y,
              const u16* __restrict__ wb,
              const float* __restrict__ qwf, const float* __restrict__ kwf,
              const float* __restrict__ vwf, const float* __restrict__ pwf,
              const float* __restrict__ qb, const float* __restrict__ kb,
              const float* __restrict__ vb, const float* __restrict__ pb,
              float* __restrict__ out)
{
  extern __shared__ char smem[];
  char* r1 = smem;                      // 32KB
  char* Xs = smem + 32768;              // 32KB
  const int b  = blockIdx.x;
  const int t  = threadIdx.x;           // 0..511
  const int w  = t >> 6;                // wave = head, 0..7
  const int l  = t & 63;
  const int lo = l & 15;
  const int g  = l >> 4;
  const u32 swr = (u32)(lo & 7) << 4;
  const int cb = w*32;                  // head channel base
  const int Rb = w*2;                   // 16-row weight block base

  const float* yb = y + (size_t)b * 16384;
  const float* xb = x + (size_t)b * 16384;

  // ---- stage Y and X -> LDS (bf16, swizzled) ----
  {
    f32x4 yr[8], xr[8];
    #pragma unroll
    for (int j = 0; j < 8; ++j){
      int idx = t + 512*j;
      yr[j] = *(const f32x4*)(yb + (idx>>6)*256 + (idx&63)*4);
    }
    #pragma unroll
    for (int j = 0; j < 8; ++j){
      int idx = t + 512*j;
      xr[j] = *(const f32x4*)(xb + (idx>>6)*256 + (idx&63)*4);
    }
    #pragma unroll
    for (int j = 0; j < 8; ++j) stw(r1, t + 512*j, yr[j]);
    #pragma unroll
    for (int j = 0; j < 8; ++j) stw(Xs, t + 512*j, xr[j]);
  }
  __syncthreads();   // Y, X readable

  // ---- Q-GEMM (this wave's head) ----
  u32x2 aqpk[8];    // [m*4+n]
  {
    f32x4 aq[2][4] = {};
    #pragma unroll
    for (int kk = 0; kk < 8; ++kk){
      bf16x8 A[2], Bf[4];
      #pragma unroll
      for (int m = 0; m < 2; ++m){
        int off = (cb + 16*m + lo)*256 + kk*32 + 8*g;
        A[m] = loadw<BW>(wfrag(wb, 0, Rb + m, kk, l), qwf + off);
      }
      #pragma unroll
      for (int n = 0; n < 4; ++n)
        Bf[n] = ld16(r1 + (16*n+lo)*512 + ((u32)(kk*64 + 16*g) ^ swr));
      #pragma unroll
      for (int m = 0; m < 2; ++m)
        #pragma unroll
        for (int n = 0; n < 4; ++n)
          aq[m][n] = mfma16(A[m], Bf[n], aq[m][n]);
    }
    #pragma unroll
    for (int m = 0; m < 2; ++m){
      f32x4 bias = *(const f32x4*)(qb + cb + 16*m + 4*g);
      #pragma unroll
      for (int n = 0; n < 4; ++n){
        f32x4 v;
        #pragma unroll
        for (int r = 0; r < 4; ++r) v[r] = (aq[m][n][r] + bias[r]) * KSCALE;
        aqpk[m*4+n] = pkfrag(v);
      }
    }
  }

  // ---- K-pass (kk-loop), then pack; then V-pass ----
  u32x2 akpk[8];    // [m*4+f]
  {
    f32x4 ak[2][4] = {};
    #pragma unroll
    for (int kk = 0; kk < 8; ++kk){
      bf16x8 WA[2], XF[4];
      #pragma unroll
      for (int m = 0; m < 2; ++m){
        int off = (cb + 16*m + lo)*256 + kk*32 + 8*g;
        WA[m] = loadw<BW>(wfrag(wb, 1, Rb + m, kk, l), kwf + off);
      }
      #pragma unroll
      for (int f = 0; f < 4; ++f)
        XF[f] = ld16(Xs + (16*f+lo)*512 + ((u32)(kk*64 + 16*g) ^ swr));
      #pragma unroll
      for (int f = 0; f < 4; ++f)
        #pragma unroll
        for (int m = 0; m < 2; ++m)
          ak[m][f] = mfma16(WA[m], XF[f], ak[m][f]);
    }
    #pragma unroll
    for (int m = 0; m < 2; ++m){
      f32x4 bias = *(const f32x4*)(kb + cb + 16*m + 4*g);
      #pragma unroll
      for (int f = 0; f < 4; ++f){
        f32x4 v;
        #pragma unroll
        for (int r = 0; r < 4; ++r) v[r] = ak[m][f][r] + bias[r];
        akpk[m*4+f] = pkfrag(v);
      }
    }
  }
  u32x2 avpk[8];    // [f*2+n]
  {
    f32x4 av[4][2] = {};
    #pragma unroll
    for (int kk = 0; kk < 8; ++kk){
      bf16x8 WB2[2], XF[4];
      #pragma unroll
      for (int n = 0; n < 2; ++n){
        int off = (cb + 16*n + lo)*256 + kk*32 + 8*g;
        WB2[n] = loadw<BW>(wfrag(wb, 2, Rb + n, kk, l), vwf + off);
      }
      #pragma unroll
      for (int f = 0; f < 4; ++f)
        XF[f] = ld16(Xs + (16*f+lo)*512 + ((u32)(kk*64 + 16*g) ^ swr));
      #pragma unroll
      for (int f = 0; f < 4; ++f)
        #pragma unroll
        for (int n = 0; n < 2; ++n)
          av[f][n] = mfma16(XF[f], WB2[n], av[f][n]);
    }
    #pragma unroll
    for (int n = 0; n < 2; ++n){
      float bias = vb[cb + 16*n + lo];
      #pragma unroll
      for (int f = 0; f < 4; ++f){
        f32x4 v;
        #pragma unroll
        for (int r = 0; r < 4; ++r) v[r] = av[f][n][r] + bias;
        avpk[f*2+n] = pkfrag(v);
      }
    }
  }
  __syncthreads();   // all Q-GEMM reads of r1(Y) and K/V reads of Xs done

  // ---- attention: per q-tile n, S (16x16x16) -> softmax+1 -> PV ----
  {
    f32x4 y1h[2][4] = {};   // [md][n] : Y1^T tiles
    #pragma unroll
    for (int n = 0; n < 4; ++n){
      f32x4 s4[4];
      #pragma unroll
      for (int f = 0; f < 4; ++f){
        f32x4 acc = {};
        acc = mfma1616(akpk[0*4+f], aqpk[0*4+n], acc);
        acc = mfma1616(akpk[1*4+f], aqpk[1*4+n], acc);
        s4[f] = acc;
      }
      float mx = s4[0][0];
      #pragma unroll
      for (int f = 0; f < 4; ++f)
        #pragma unroll
        for (int r = 0; r < 4; ++r)
          mx = fmaxf(mx, s4[f][r]);
      mx = fmaxf(mx, __shfl_xor(mx, 16));
      mx = fmaxf(mx, __shfl_xor(mx, 32));
      float sum = 0.f;
      #pragma unroll
      for (int f = 0; f < 4; ++f)
        #pragma unroll
        for (int r = 0; r < 4; ++r){
          float e = __expf(s4[f][r] - mx);
          s4[f][r] = e; sum += e;
        }
      sum += __shfl_xor(sum, 16);
      sum += __shfl_xor(sum, 32);
      float rin = 1.0f / (sum + 1.0f);
      u32x2 spk[4];
      #pragma unroll
      for (int f = 0; f < 4; ++f){
        f32x4 v;
        #pragma unroll
        for (int r = 0; r < 4; ++r) v[r] = s4[f][r] * rin;
        spk[f] = pkfrag(v);
      }
      #pragma unroll
      for (int md = 0; md < 2; ++md)
        #pragma unroll
        for (int f = 0; f < 4; ++f)
          y1h[md][n] = mfma1616(avpk[f*2+md], spk[f], y1h[md][n]);
    }

    // ---- residual: r1 += y1 (wave-private cols [32w,32w+32)) ----
    #pragma unroll
    for (int md = 0; md < 2; ++md)
      #pragma unroll
      for (int n = 0; n < 4; ++n){
        int c0 = cb + 16*md + 4*g;
        char* p = r1 + (16*n+lo)*512 + ((u32)(c0*2) ^ swr);
        u32x2 old = *(const u32x2*)p;
        f32x4 a = y1h[md][n];
        float o0 = bfl(old[0] & 0xffffu) + a[0];
        float o1 = bfl(old[0] >> 16)     + a[1];
        float o2 = bfl(old[1] & 0xffffu) + a[2];
        float o3 = bfl(old[1] >> 16)     + a[3];
        u32x2 nw; nw[0] = pk2(o0, o1); nw[1] = pk2(o2, o3);
        *(u32x2*)p = nw;
      }
  }
  __syncthreads();   // residual writes visible to all

  // ---- proj: out[:, 32w..32w+32) = r1 @ proj_w^T + proj_b ----
  f32x4 ap[4][2] = {};
  #pragma unroll
  for (int kk = 0; kk < 8; ++kk){
    bf16x8 Af[4], Bp[2];
    #pragma unroll
    for (int m = 0; m < 4; ++m)
      Af[m] = ld16(r1 + (16*m+lo)*512 + ((u32)(kk*64 + 16*g) ^ swr));
    #pragma unroll
    for (int n = 0; n < 2; ++n){
      int off = (cb + 16*n + lo)*256 + kk*32 + 8*g;
      Bp[n] = loadw<BW>(wfrag(wb, 3, Rb + n, kk, l), pwf + off);
    }
    #pragma unroll
    for (int m = 0; m < 4; ++m)
      #pragma unroll
      for (int n = 0; n < 2; ++n)
        ap[m][n] = mfma16(Af[m], Bp[n], ap[m][n]);
  }
  {
    float pbv[2];
    #pragma unroll
    for (int n = 0; n < 2; ++n) pbv[n] = pb[cb + 16*n + lo];
    #pragma unroll
    for (int m = 0; m < 4; ++m)
      #pragma unroll
      for (int n = 0; n < 2; ++n)
        #pragma unroll
        for (int r = 0; r < 4; ++r)
          ap[m][n][r] += pbv[n];
  }

  // ---- coalesced store via LDS transpose (all 64KB reused as [64][256] f32) ----
  float* ob = out + (size_t)b * 16384;
  __syncthreads();   // proj reads of r1 done everywhere
  #pragma unroll
  for (int m = 0; m < 4; ++m)
    #pragma unroll
    for (int n = 0; n < 2; ++n){
      int col = cb + 16*n + lo;
      #pragma unroll
      for (int r = 0; r < 4; ++r){
        int row = 16*m + 4*g + r;                         // 0..63
        u32 byteoff = ((u32)(row*1024 + col*4)) ^ ((u32)(row & 4) << 4);
        *(float*)(smem + byteoff) = ap[m][n][r];
      }
    }
  __syncthreads();
  #pragma unroll
  for (int i = 0; i < 8; ++i){
    int id  = i*512 + t;
    int row = id >> 6;                                    // 0..63
    int cc  = id & 63;
    u32 byteoff = (u32)(row*1024) + ((u32)(cc ^ (row & 4)) << 4);
    f32x4 v = *(const f32x4*)(smem + byteoff);
    *(f32x4*)(ob + row*256 + cc*4) = v;
  }
}

extern "C" void kernel_launch(void* const* d_in, const int* in_sizes, int n_in,
                              void* d_out, int out_size, void* d_ws, size_t ws_size,
                              hipStream_t stream) {
  (void)n_in; (void)out_size;
  const float* x  = (const float*)d_in[0];
  const float* y  = (const float*)d_in[1];
  // d_in[2] (z) is unused by the reference forward
  const float* qw = (const float*)d_in[3];
  const float* qb = (const float*)d_in[4];
  const float* kw = (const float*)d_in[5];
  const float* kb = (const float*)d_in[6];
  const float* vw = (const float*)d_in[7];
  const float* vb = (const float*)d_in[8];
  const float* pw = (const float*)d_in[9];
  const float* pb = (const float*)d_in[10];
  float* out = (float*)d_out;
  const int Bn = in_sizes[0] / 16384;   // 2048

  const bool useWs = ws_size >= (size_t)524288;
  if (useWs){
    u16* wsb = (u16*)d_ws;
    prep_w<<<512, 64, 0, stream>>>(qw, kw, vw, pw, wsb);
    (void)hipFuncSetAttribute(reinterpret_cast<const void*>(&fused_ca<true>),
                              hipFuncAttributeMaxDynamicSharedMemorySize, 65536);
    fused_ca<true><<<Bn, 512, 65536, stream>>>(x, y, wsb, qw, kw, vw, pw,
                                               qb, kb, vb, pb, out);
  } else {
    (void)hipFuncSetAttribute(reinterpret_cast<const void*>(&fused_ca<false>),
                              hipFuncAttributeMaxDynamicSharedMemorySize, 65536);
    fused_ca<false><<<Bn, 512, 65536, stream>>>(x, y, (const u16*)d_ws, qw, kw, vw, pw,
                                                qb, kb, vb, pb, out);
  }
}

// Round 7
// 192.130 us; speedup vs baseline: 2.2132x; 1.2306x over previous
//
#include <hip/hip_runtime.h>

typedef __bf16 bf16x8 __attribute__((ext_vector_type(8)));
typedef __bf16 bf16x4 __attribute__((ext_vector_type(4)));
typedef short  s16x4  __attribute__((ext_vector_type(4)));
typedef float  f32x4  __attribute__((ext_vector_type(4)));
typedef unsigned int u32x4 __attribute__((ext_vector_type(4)));
typedef unsigned int u32x2 __attribute__((ext_vector_type(2)));
typedef unsigned int u32;
typedef unsigned short u16;

#define DEVI static __device__ __forceinline__

// Bn=2048, L=64, C=256, NH=8, HD=32
static constexpr float KSCALE = 0.17677669529663687f;  // 32^-0.5

DEVI u32 pk2(float a, float b){
  u16 ha = __builtin_bit_cast(u16, (__bf16)a);
  u16 hb = __builtin_bit_cast(u16, (__bf16)b);
  return (u32)ha | ((u32)hb << 16);
}
DEVI float bfl(u32 bits16){            // low 16 bits hold a bf16
  union { u32 i; float f; } v; v.i = bits16 << 16; return v.f;
}
DEVI u32x2 pkfrag(f32x4 v){ u32x2 o; o[0]=pk2(v[0],v[1]); o[1]=pk2(v[2],v[3]); return o; }
DEVI bf16x8 ld16(const void* p){ return __builtin_bit_cast(bf16x8, *(const u32x4*)p); }
DEVI f32x4 mfma16(bf16x8 a, bf16x8 b, f32x4 c){
  return __builtin_amdgcn_mfma_f32_16x16x32_bf16(a, b, c, 0, 0, 0);
}
// 16x16x16 bf16 MFMA: A/B frag layout is the transpose of the C/D layout ->
// S and PV consume Q/K/V/P straight from accumulator registers.
DEVI f32x4 mfma1616(u32x2 a, u32x2 b, f32x4 c){
#if __has_builtin(__builtin_amdgcn_mfma_f32_16x16x16_bf16)
  return __builtin_amdgcn_mfma_f32_16x16x16_bf16(
      __builtin_bit_cast(bf16x4, a), __builtin_bit_cast(bf16x4, b), c, 0, 0, 0);
#elif __has_builtin(__builtin_amdgcn_mfma_f32_16x16x16bf16_1k)
  return __builtin_amdgcn_mfma_f32_16x16x16bf16_1k(
      __builtin_bit_cast(s16x4, a), __builtin_bit_cast(s16x4, b), c, 0, 0, 0);
#else
  asm("v_mfma_f32_16x16x16_bf16 %0, %1, %2, %0" : "+v"(c) : "v"(a), "v"(b));
  return c;
#endif
}

template<bool BW>
DEVI bf16x8 loadw(const u16* wbp, const float* wfp){
  if constexpr (BW){
    return ld16(wbp);
  } else {
    f32x4 a = *(const f32x4*)wfp;
    f32x4 b = *(const f32x4*)(wfp + 4);
    u32x4 pc; pc[0]=pk2(a[0],a[1]); pc[1]=pk2(a[2],a[3]); pc[2]=pk2(b[0],b[1]); pc[3]=pk2(b[2],b[3]);
    return __builtin_bit_cast(bf16x8, pc);
  }
}

// Permuted weight layout: frag block (M, R, kk) is 1KB contiguous, lane-major:
//   dst[(((M*16+R)*8+kk)*64 + l)*8 + e] = W_M[R*16 + (l&15)][kk*32 + (l>>4)*8 + e]
__global__ void prep_w(const float* __restrict__ qw, const float* __restrict__ kw,
                       const float* __restrict__ vw, const float* __restrict__ pw,
                       u16* __restrict__ dst){
  int blk = blockIdx.x;            // 512 blocks: M(2b) R(4b) kk(3b)
  int l   = threadIdx.x;           // 64
  int M = blk >> 7, R = (blk >> 3) & 15, kk = blk & 7;
  const float* W = (M==0) ? qw : (M==1) ? kw : (M==2) ? vw : pw;
  const float* src = W + (R*16 + (l&15))*256 + kk*32 + (l>>4)*8;
  f32x4 a  = *(const f32x4*)src;
  f32x4 b2 = *(const f32x4*)(src + 4);
  u32x4 pc; pc[0]=pk2(a[0],a[1]); pc[1]=pk2(a[2],a[3]); pc[2]=pk2(b2[0],b2[1]); pc[3]=pk2(b2[2],b2[3]);
  *(u32x4*)(dst + (size_t)blk*512 + l*8) = pc;
}

DEVI const u16* wfrag(const u16* wb, int M, int R, int kk, int l){
  return wb + ((((M<<4) + R)<<3) + kk)*512 + l*8;
}

DEVI void stw(char* T, int idx, f32x4 v){   // pack f32x4 -> bf16x4, swizzled store
  int row = idx >> 6;
  int c0  = (idx & 63) * 4;
  u32x2 o; o[0] = pk2(v[0], v[1]); o[1] = pk2(v[2], v[3]);
  *(u32x2*)(T + row*512 + ((u32)(c0*2) ^ ((u32)(row&7) << 4))) = o;
}

// One block per batch item. 512 threads = 8 waves; wave w owns head w (cols
// [32w, 32w+32)). LDS 64KB: r1 = Y/(Y+Y1) bf16 [64][256] pitch 512B swizzled;
// Xs = X bf16 same layout. Epilogue reuses all 64KB as [64][256] f32 out-stage.
// Q/K/V/P never touch LDS (16x16x16 register-fragment trick). K-pass and
// V-pass are separate kk-loops to keep peak live regs under the 128 cap.
// NOTE: __launch_bounds__ 2nd arg acts as min BLOCKS/CU on this toolchain
// (R6 evidence: (512,4) -> 64-VGPR cap -> 300MB spills). (512,2) -> 128 cap.
template<bool BW>
__global__ __launch_bounds__(512, 2)
void fused_ca(const float* __restrict__ x, const float* __restrict__ y,
              const u16* __restrict__ wb,
              const float* __restrict__ qwf, const float* __restrict__ kwf,
              const float* __restrict__ vwf, const float* __restrict__ pwf,
              const float* __restrict__ qb, const float* __restrict__ kb,
              const float* __restrict__ vb, const float* __restrict__ pb,
              float* __restrict__ out)
{
  extern __shared__ char smem[];
  char* r1 = smem;                      // 32KB
  char* Xs = smem + 32768;              // 32KB
  const int b  = blockIdx.x;
  const int t  = threadIdx.x;           // 0..511
  const int w  = t >> 6;                // wave = head, 0..7
  const int l  = t & 63;
  const int lo = l & 15;
  const int g  = l >> 4;
  const u32 swr = (u32)(lo & 7) << 4;
  const int cb = w*32;                  // head channel base
  const int Rb = w*2;                   // 16-row weight block base

  const float* yb = y + (size_t)b * 16384;
  const float* xb = x + (size_t)b * 16384;

  // ---- stage Y and X -> LDS (bf16, swizzled) ----
  {
    f32x4 yr[8], xr[8];
    #pragma unroll
    for (int j = 0; j < 8; ++j){
      int idx = t + 512*j;
      yr[j] = *(const f32x4*)(yb + (idx>>6)*256 + (idx&63)*4);
    }
    #pragma unroll
    for (int j = 0; j < 8; ++j){
      int idx = t + 512*j;
      xr[j] = *(const f32x4*)(xb + (idx>>6)*256 + (idx&63)*4);
    }
    #pragma unroll
    for (int j = 0; j < 8; ++j) stw(r1, t + 512*j, yr[j]);
    #pragma unroll
    for (int j = 0; j < 8; ++j) stw(Xs, t + 512*j, xr[j]);
  }
  __syncthreads();   // Y, X readable

  // ---- Q-GEMM (this wave's head) ----
  u32x2 aqpk[8];    // [m*4+n]
  {
    f32x4 aq[2][4] = {};
    #pragma unroll
    for (int kk = 0; kk < 8; ++kk){
      bf16x8 A[2], Bf[4];
      #pragma unroll
      for (int m = 0; m < 2; ++m){
        int off = (cb + 16*m + lo)*256 + kk*32 + 8*g;
        A[m] = loadw<BW>(wfrag(wb, 0, Rb + m, kk, l), qwf + off);
      }
      #pragma unroll
      for (int n = 0; n < 4; ++n)
        Bf[n] = ld16(r1 + (16*n+lo)*512 + ((u32)(kk*64 + 16*g) ^ swr));
      #pragma unroll
      for (int m = 0; m < 2; ++m)
        #pragma unroll
        for (int n = 0; n < 4; ++n)
          aq[m][n] = mfma16(A[m], Bf[n], aq[m][n]);
    }
    #pragma unroll
    for (int m = 0; m < 2; ++m){
      f32x4 bias = *(const f32x4*)(qb + cb + 16*m + 4*g);
      #pragma unroll
      for (int n = 0; n < 4; ++n){
        f32x4 v;
        #pragma unroll
        for (int r = 0; r < 4; ++r) v[r] = (aq[m][n][r] + bias[r]) * KSCALE;
        aqpk[m*4+n] = pkfrag(v);
      }
    }
  }

  // ---- K-pass (kk-loop), then pack; then V-pass ----
  u32x2 akpk[8];    // [m*4+f]
  {
    f32x4 ak[2][4] = {};
    #pragma unroll
    for (int kk = 0; kk < 8; ++kk){
      bf16x8 WA[2], XF[4];
      #pragma unroll
      for (int m = 0; m < 2; ++m){
        int off = (cb + 16*m + lo)*256 + kk*32 + 8*g;
        WA[m] = loadw<BW>(wfrag(wb, 1, Rb + m, kk, l), kwf + off);
      }
      #pragma unroll
      for (int f = 0; f < 4; ++f)
        XF[f] = ld16(Xs + (16*f+lo)*512 + ((u32)(kk*64 + 16*g) ^ swr));
      #pragma unroll
      for (int f = 0; f < 4; ++f)
        #pragma unroll
        for (int m = 0; m < 2; ++m)
          ak[m][f] = mfma16(WA[m], XF[f], ak[m][f]);
    }
    #pragma unroll
    for (int m = 0; m < 2; ++m){
      f32x4 bias = *(const f32x4*)(kb + cb + 16*m + 4*g);
      #pragma unroll
      for (int f = 0; f < 4; ++f){
        f32x4 v;
        #pragma unroll
        for (int r = 0; r < 4; ++r) v[r] = ak[m][f][r] + bias[r];
        akpk[m*4+f] = pkfrag(v);
      }
    }
  }
  u32x2 avpk[8];    // [f*2+n]
  {
    f32x4 av[4][2] = {};
    #pragma unroll
    for (int kk = 0; kk < 8; ++kk){
      bf16x8 WB2[2], XF[4];
      #pragma unroll
      for (int n = 0; n < 2; ++n){
        int off = (cb + 16*n + lo)*256 + kk*32 + 8*g;
        WB2[n] = loadw<BW>(wfrag(wb, 2, Rb + n, kk, l), vwf + off);
      }
      #pragma unroll
      for (int f = 0; f < 4; ++f)
        XF[f] = ld16(Xs + (16*f+lo)*512 + ((u32)(kk*64 + 16*g) ^ swr));
      #pragma unroll
      for (int f = 0; f < 4; ++f)
        #pragma unroll
        for (int n = 0; n < 2; ++n)
          av[f][n] = mfma16(XF[f], WB2[n], av[f][n]);
    }
    #pragma unroll
    for (int n = 0; n < 2; ++n){
      float bias = vb[cb + 16*n + lo];
      #pragma unroll
      for (int f = 0; f < 4; ++f){
        f32x4 v;
        #pragma unroll
        for (int r = 0; r < 4; ++r) v[r] = av[f][n][r] + bias;
        avpk[f*2+n] = pkfrag(v);
      }
    }
  }
  __syncthreads();   // all Q-GEMM reads of r1(Y) and K/V reads of Xs done

  // ---- attention: per q-tile n, S (16x16x16) -> softmax+1 -> PV ----
  {
    f32x4 y1h[2][4] = {};   // [md][n] : Y1^T tiles
    #pragma unroll
    for (int n = 0; n < 4; ++n){
      f32x4 s4[4];
      #pragma unroll
      for (int f = 0; f < 4; ++f){
        f32x4 acc = {};
        acc = mfma1616(akpk[0*4+f], aqpk[0*4+n], acc);
        acc = mfma1616(akpk[1*4+f], aqpk[1*4+n], acc);
        s4[f] = acc;
      }
      float mx = s4[0][0];
      #pragma unroll
      for (int f = 0; f < 4; ++f)
        #pragma unroll
        for (int r = 0; r < 4; ++r)
          mx = fmaxf(mx, s4[f][r]);
      mx = fmaxf(mx, __shfl_xor(mx, 16));
      mx = fmaxf(mx, __shfl_xor(mx, 32));
      float sum = 0.f;
      #pragma unroll
      for (int f = 0; f < 4; ++f)
        #pragma unroll
        for (int r = 0; r < 4; ++r){
          float e = __expf(s4[f][r] - mx);
          s4[f][r] = e; sum += e;
        }
      sum += __shfl_xor(sum, 16);
      sum += __shfl_xor(sum, 32);
      float rin = 1.0f / (sum + 1.0f);
      u32x2 spk[4];
      #pragma unroll
      for (int f = 0; f < 4; ++f){
        f32x4 v;
        #pragma unroll
        for (int r = 0; r < 4; ++r) v[r] = s4[f][r] * rin;
        spk[f] = pkfrag(v);
      }
      #pragma unroll
      for (int md = 0; md < 2; ++md)
        #pragma unroll
        for (int f = 0; f < 4; ++f)
          y1h[md][n] = mfma1616(avpk[f*2+md], spk[f], y1h[md][n]);
    }

    // ---- residual: r1 += y1 (wave-private cols [32w,32w+32)) ----
    #pragma unroll
    for (int md = 0; md < 2; ++md)
      #pragma unroll
      for (int n = 0; n < 4; ++n){
        int c0 = cb + 16*md + 4*g;
        char* p = r1 + (16*n+lo)*512 + ((u32)(c0*2) ^ swr);
        u32x2 old = *(const u32x2*)p;
        f32x4 a = y1h[md][n];
        float o0 = bfl(old[0] & 0xffffu) + a[0];
        float o1 = bfl(old[0] >> 16)     + a[1];
        float o2 = bfl(old[1] & 0xffffu) + a[2];
        float o3 = bfl(old[1] >> 16)     + a[3];
        u32x2 nw; nw[0] = pk2(o0, o1); nw[1] = pk2(o2, o3);
        *(u32x2*)p = nw;
      }
  }
  __syncthreads();   // residual writes visible to all

  // ---- proj: out[:, 32w..32w+32) = r1 @ proj_w^T + proj_b ----
  f32x4 ap[4][2] = {};
  #pragma unroll
  for (int kk = 0; kk < 8; ++kk){
    bf16x8 Af[4], Bp[2];
    #pragma unroll
    for (int m = 0; m < 4; ++m)
      Af[m] = ld16(r1 + (16*m+lo)*512 + ((u32)(kk*64 + 16*g) ^ swr));
    #pragma unroll
    for (int n = 0; n < 2; ++n){
      int off = (cb + 16*n + lo)*256 + kk*32 + 8*g;
      Bp[n] = loadw<BW>(wfrag(wb, 3, Rb + n, kk, l), pwf + off);
    }
    #pragma unroll
    for (int m = 0; m < 4; ++m)
      #pragma unroll
      for (int n = 0; n < 2; ++n)
        ap[m][n] = mfma16(Af[m], Bp[n], ap[m][n]);
  }
  {
    float pbv[2];
    #pragma unroll
    for (int n = 0; n < 2; ++n) pbv[n] = pb[cb + 16*n + lo];
    #pragma unroll
    for (int m = 0; m < 4; ++m)
      #pragma unroll
      for (int n = 0; n < 2; ++n)
        #pragma unroll
        for (int r = 0; r < 4; ++r)
          ap[m][n][r] += pbv[n];
  }

  // ---- coalesced store via LDS transpose (all 64KB reused as [64][256] f32) ----
  float* ob = out + (size_t)b * 16384;
  __syncthreads();   // proj reads of r1 done everywhere
  #pragma unroll
  for (int m = 0; m < 4; ++m)
    #pragma unroll
    for (int n = 0; n < 2; ++n){
      int col = cb + 16*n + lo;
      #pragma unroll
      for (int r = 0; r < 4; ++r){
        int row = 16*m + 4*g + r;                         // 0..63
        u32 byteoff = ((u32)(row*1024 + col*4)) ^ ((u32)(row & 4) << 4);
        *(float*)(smem + byteoff) = ap[m][n][r];
      }
    }
  __syncthreads();
  #pragma unroll
  for (int i = 0; i < 8; ++i){
    int id  = i*512 + t;
    int row = id >> 6;                                    // 0..63
    int cc  = id & 63;
    u32 byteoff = (u32)(row*1024) + ((u32)(cc ^ (row & 4)) << 4);
    f32x4 v = *(const f32x4*)(smem + byteoff);
    *(f32x4*)(ob + row*256 + cc*4) = v;
  }
}

extern "C" void kernel_launch(void* const* d_in, const int* in_sizes, int n_in,
                              void* d_out, int out_size, void* d_ws, size_t ws_size,
                              hipStream_t stream) {
  (void)n_in; (void)out_size;
  const float* x  = (const float*)d_in[0];
  const float* y  = (const float*)d_in[1];
  // d_in[2] (z) is unused by the reference forward
  const float* qw = (const float*)d_in[3];
  const float* qb = (const float*)d_in[4];
  const float* kw = (const float*)d_in[5];
  const float* kb = (const float*)d_in[6];
  const float* vw = (const float*)d_in[7];
  const float* vb = (const float*)d_in[8];
  const float* pw = (const float*)d_in[9];
  const float* pb = (const float*)d_in[10];
  float* out = (float*)d_out;
  const int Bn = in_sizes[0] / 16384;   // 2048

  const bool useWs = ws_size >= (size_t)524288;
  if (useWs){
    u16* wsb = (u16*)d_ws;
    prep_w<<<512, 64, 0, stream>>>(qw, kw, vw, pw, wsb);
    (void)hipFuncSetAttribute(reinterpret_cast<const void*>(&fused_ca<true>),
                              hipFuncAttributeMaxDynamicSharedMemorySize, 65536);
    fused_ca<true><<<Bn, 512, 65536, stream>>>(x, y, wsb, qw, kw, vw, pw,
                                               qb, kb, vb, pb, out);
  } else {
    (void)hipFuncSetAttribute(reinterpret_cast<const void*>(&fused_ca<false>),
                              hipFuncAttributeMaxDynamicSharedMemorySize, 65536);
    fused_ca<false><<<Bn, 512, 65536, stream>>>(x, y, (const u16*)d_ws, qw, kw, vw, pw,
                                                qb, kb, vb, pb, out);
  }
}

// Round 8
// 189.572 us; speedup vs baseline: 2.2430x; 1.0135x over previous
//
#include <hip/hip_runtime.h>

typedef __bf16 bf16x8 __attribute__((ext_vector_type(8)));
typedef __bf16 bf16x4 __attribute__((ext_vector_type(4)));
typedef short  s16x4  __attribute__((ext_vector_type(4)));
typedef float  f32x4  __attribute__((ext_vector_type(4)));
typedef unsigned int u32x4 __attribute__((ext_vector_type(4)));
typedef unsigned int u32x2 __attribute__((ext_vector_type(2)));
typedef unsigned int u32;
typedef unsigned short u16;

#define DEVI static __device__ __forceinline__

// Bn=2048, L=64, C=256, NH=8, HD=32
static constexpr float KSCALE = 0.17677669529663687f;  // 32^-0.5

DEVI u32 pk2(float a, float b){
  u16 ha = __builtin_bit_cast(u16, (__bf16)a);
  u16 hb = __builtin_bit_cast(u16, (__bf16)b);
  return (u32)ha | ((u32)hb << 16);
}
DEVI float bfl(u32 bits16){            // low 16 bits hold a bf16
  union { u32 i; float f; } v; v.i = bits16 << 16; return v.f;
}
DEVI u32x2 pkfrag(f32x4 v){ u32x2 o; o[0]=pk2(v[0],v[1]); o[1]=pk2(v[2],v[3]); return o; }
DEVI bf16x8 ld16(const void* p){ return __builtin_bit_cast(bf16x8, *(const u32x4*)p); }
DEVI f32x4 mfma16(bf16x8 a, bf16x8 b, f32x4 c){
  return __builtin_amdgcn_mfma_f32_16x16x32_bf16(a, b, c, 0, 0, 0);
}
// 16x16x16 bf16 MFMA: A/B frag layout is the transpose of the C/D layout ->
// S and PV consume Q/K/V/P straight from accumulator registers.
DEVI f32x4 mfma1616(u32x2 a, u32x2 b, f32x4 c){
#if __has_builtin(__builtin_amdgcn_mfma_f32_16x16x16_bf16)
  return __builtin_amdgcn_mfma_f32_16x16x16_bf16(
      __builtin_bit_cast(bf16x4, a), __builtin_bit_cast(bf16x4, b), c, 0, 0, 0);
#elif __has_builtin(__builtin_amdgcn_mfma_f32_16x16x16bf16_1k)
  return __builtin_amdgcn_mfma_f32_16x16x16bf16_1k(
      __builtin_bit_cast(s16x4, a), __builtin_bit_cast(s16x4, b), c, 0, 0, 0);
#else
  asm("v_mfma_f32_16x16x16_bf16 %0, %1, %2, %0" : "+v"(c) : "v"(a), "v"(b));
  return c;
#endif
}

template<bool BW>
DEVI bf16x8 loadw(const u16* wbp, const float* wfp){
  if constexpr (BW){
    return ld16(wbp);
  } else {
    f32x4 a = *(const f32x4*)wfp;
    f32x4 b = *(const f32x4*)(wfp + 4);
    u32x4 pc; pc[0]=pk2(a[0],a[1]); pc[1]=pk2(a[2],a[3]); pc[2]=pk2(b[0],b[1]); pc[3]=pk2(b[2],b[3]);
    return __builtin_bit_cast(bf16x8, pc);
  }
}

// Permuted weight layout: frag block (M, R, kk) is 1KB contiguous, lane-major:
//   dst[(((M*16+R)*8+kk)*64 + l)*8 + e] = W_M[R*16 + (l&15)][kk*32 + (l>>4)*8 + e]
__global__ void prep_w(const float* __restrict__ qw, const float* __restrict__ kw,
                       const float* __restrict__ vw, const float* __restrict__ pw,
                       u16* __restrict__ dst){
  int blk = blockIdx.x;            // 512 blocks: M(2b) R(4b) kk(3b)
  int l   = threadIdx.x;           // 64
  int M = blk >> 7, R = (blk >> 3) & 15, kk = blk & 7;
  const float* W = (M==0) ? qw : (M==1) ? kw : (M==2) ? vw : pw;
  const float* src = W + (R*16 + (l&15))*256 + kk*32 + (l>>4)*8;
  f32x4 a  = *(const f32x4*)src;
  f32x4 b2 = *(const f32x4*)(src + 4);
  u32x4 pc; pc[0]=pk2(a[0],a[1]); pc[1]=pk2(a[2],a[3]); pc[2]=pk2(b2[0],b2[1]); pc[3]=pk2(b2[2],b2[3]);
  *(u32x4*)(dst + (size_t)blk*512 + l*8) = pc;
}

DEVI const u16* wfrag(const u16* wb, int M, int R, int kk, int l){
  return wb + ((((M<<4) + R)<<3) + kk)*512 + l*8;
}

DEVI void stw(char* T, int idx, f32x4 v){   // pack f32x4 -> bf16x4, swizzled store
  int row = idx >> 6;
  int c0  = (idx & 63) * 4;
  u32x2 o; o[0] = pk2(v[0], v[1]); o[1] = pk2(v[2], v[3]);
  *(u32x2*)(T + row*512 + ((u32)(c0*2) ^ ((u32)(row&7) << 4))) = o;
}

// One block per batch item. 256 threads = 4 waves; wave w owns heads {2w,2w+1}.
// LDS 48KB: r1 = Y/(Y+Y1) bf16 [64][256] pitch 512B swizzled (32KB);
// Xs = ONE 32-row half of X, [32][256] bf16 (16KB), time-shared between the
// two token halves of the K/V GEMM. 48KB -> 3 blocks/CU (vs R3's 64KB -> 2).
// Q/K/V/P never touch LDS (16x16x16 register-fragment trick).
// __launch_bounds__(256,2): cap 256 regs -- no forced squeeze (spill-safe);
// 3 blocks/CU materialize iff natural allocation <= 170.
template<bool BW>
__global__ __launch_bounds__(256, 2)
void fused_ca(const float* __restrict__ x, const float* __restrict__ y,
              const u16* __restrict__ wb,
              const float* __restrict__ qwf, const float* __restrict__ kwf,
              const float* __restrict__ vwf, const float* __restrict__ pwf,
              const float* __restrict__ qb, const float* __restrict__ kb,
              const float* __restrict__ vb, const float* __restrict__ pb,
              float* __restrict__ out)
{
  extern __shared__ char smem[];
  char* r1 = smem;                      // 32KB
  char* Xs = smem + 32768;              // 16KB (one half of X)
  const int b  = blockIdx.x;
  const int t  = threadIdx.x;
  const int w  = t >> 6;
  const int l  = t & 63;
  const int lo = l & 15;
  const int g  = l >> 4;
  const u32 swr = (u32)(lo & 7) << 4;

  const float* yb = y + (size_t)b * 16384;
  const float* xb = x + (size_t)b * 16384;

  // ---- P0: stage Y (rows 0..63) and X half0 (rows 0..31) ----
  {
    f32x4 x0r[8];
    #pragma unroll
    for (int j = 0; j < 8; ++j){
      int idx = t + 256*j;
      x0r[j] = *(const f32x4*)(xb + (idx>>6)*256 + (idx&63)*4);
    }
    #pragma unroll
    for (int j = 0; j < 16; ++j){
      int idx = t + 256*j;
      f32x4 v = *(const f32x4*)(yb + (idx>>6)*256 + (idx&63)*4);
      stw(r1, idx, v);
    }
    #pragma unroll
    for (int j = 0; j < 8; ++j) stw(Xs, t + 256*j, x0r[j]);
  }
  __syncthreads();   // Y, X0 readable

  // ---- P1: Q-GEMMs (both heads) ----
  u32x2 aqpk[2][8];    // [hl][m*4+n]
  #pragma unroll
  for (int hl = 0; hl < 2; ++hl){
    const int cb = w*64 + hl*32;
    const int Rb = w*4 + hl*2;
    f32x4 aq[2][4] = {};
    #pragma unroll
    for (int kk = 0; kk < 8; ++kk){
      bf16x8 A[2], Bf[4];
      #pragma unroll
      for (int m = 0; m < 2; ++m){
        int off = (cb + 16*m + lo)*256 + kk*32 + 8*g;
        A[m] = loadw<BW>(wfrag(wb, 0, Rb + m, kk, l), qwf + off);
      }
      #pragma unroll
      for (int n = 0; n < 4; ++n)
        Bf[n] = ld16(r1 + (16*n+lo)*512 + ((u32)(kk*64 + 16*g) ^ swr));
      #pragma unroll
      for (int m = 0; m < 2; ++m)
        #pragma unroll
        for (int n = 0; n < 4; ++n)
          aq[m][n] = mfma16(A[m], Bf[n], aq[m][n]);
    }
    #pragma unroll
    for (int m = 0; m < 2; ++m){
      f32x4 bias = *(const f32x4*)(qb + cb + 16*m + 4*g);
      #pragma unroll
      for (int n = 0; n < 4; ++n){
        f32x4 v;
        #pragma unroll
        for (int r = 0; r < 4; ++r) v[r] = (aq[m][n][r] + bias[r]) * KSCALE;
        aqpk[hl][m*4+n] = pkfrag(v);
      }
    }
  }

  // ---- P2: issue X half1 loads; K/V GEMM on token half0 (f=0,1), both heads ----
  u32x2 akpk[2][8], avpk[2][8];   // [hl][m*4+f], [hl][f*2+n]
  f32x4 x1r[8];
  #pragma unroll
  for (int j = 0; j < 8; ++j){
    int idx = 2048 + t + 256*j;          // global rows 32..63
    x1r[j] = *(const f32x4*)(xb + (idx>>6)*256 + (idx&63)*4);
  }
  {
    f32x4 ak[2][2][2] = {};   // [hl][m][fl]
    f32x4 av[2][2][2] = {};   // [hl][fl][n]
    #pragma unroll
    for (int kk = 0; kk < 8; ++kk){
      bf16x8 XF[2];
      #pragma unroll
      for (int fl = 0; fl < 2; ++fl)
        XF[fl] = ld16(Xs + (16*fl+lo)*512 + ((u32)(kk*64 + 16*g) ^ swr));
      #pragma unroll
      for (int hl = 0; hl < 2; ++hl){
        const int cb = w*64 + hl*32;
        const int Rb = w*4 + hl*2;
        bf16x8 WA[2], WB2[2];
        #pragma unroll
        for (int m = 0; m < 2; ++m){
          int off = (cb + 16*m + lo)*256 + kk*32 + 8*g;
          WA[m] = loadw<BW>(wfrag(wb, 1, Rb + m, kk, l), kwf + off);
        }
        #pragma unroll
        for (int n = 0; n < 2; ++n){
          int off = (cb + 16*n + lo)*256 + kk*32 + 8*g;
          WB2[n] = loadw<BW>(wfrag(wb, 2, Rb + n, kk, l), vwf + off);
        }
        #pragma unroll
        for (int fl = 0; fl < 2; ++fl){
          #pragma unroll
          for (int m = 0; m < 2; ++m)
            ak[hl][m][fl] = mfma16(WA[m], XF[fl], ak[hl][m][fl]);
          #pragma unroll
          for (int n = 0; n < 2; ++n)
            av[hl][fl][n] = mfma16(XF[fl], WB2[n], av[hl][fl][n]);
        }
      }
    }
    #pragma unroll
    for (int hl = 0; hl < 2; ++hl){
      const int cb = w*64 + hl*32;
      #pragma unroll
      for (int m = 0; m < 2; ++m){
        f32x4 bias = *(const f32x4*)(kb + cb + 16*m + 4*g);
        #pragma unroll
        for (int fl = 0; fl < 2; ++fl){
          f32x4 v;
          #pragma unroll
          for (int r = 0; r < 4; ++r) v[r] = ak[hl][m][fl][r] + bias[r];
          akpk[hl][m*4+fl] = pkfrag(v);
        }
      }
      #pragma unroll
      for (int n = 0; n < 2; ++n){
        float bias = vb[cb + 16*n + lo];
        #pragma unroll
        for (int fl = 0; fl < 2; ++fl){
          f32x4 v;
          #pragma unroll
          for (int r = 0; r < 4; ++r) v[r] = av[hl][fl][n][r] + bias;
          avpk[hl][fl*2+n] = pkfrag(v);
        }
      }
    }
  }
  __syncthreads();   // X0 reads done everywhere (also: all Q r1-reads done)

  // ---- P2b: write X half1 into Xs ----
  #pragma unroll
  for (int j = 0; j < 8; ++j) stw(Xs, t + 256*j, x1r[j]);
  __syncthreads();   // X1 readable

  // ---- P3: K/V GEMM on token half1 (f=2,3), both heads ----
  {
    f32x4 ak[2][2][2] = {};
    f32x4 av[2][2][2] = {};
    #pragma unroll
    for (int kk = 0; kk < 8; ++kk){
      bf16x8 XF[2];
      #pragma unroll
      for (int fl = 0; fl < 2; ++fl)
        XF[fl] = ld16(Xs + (16*fl+lo)*512 + ((u32)(kk*64 + 16*g) ^ swr));
      #pragma unroll
      for (int hl = 0; hl < 2; ++hl){
        const int cb = w*64 + hl*32;
        const int Rb = w*4 + hl*2;
        bf16x8 WA[2], WB2[2];
        #pragma unroll
        for (int m = 0; m < 2; ++m){
          int off = (cb + 16*m + lo)*256 + kk*32 + 8*g;
          WA[m] = loadw<BW>(wfrag(wb, 1, Rb + m, kk, l), kwf + off);
        }
        #pragma unroll
        for (int n = 0; n < 2; ++n){
          int off = (cb + 16*n + lo)*256 + kk*32 + 8*g;
          WB2[n] = loadw<BW>(wfrag(wb, 2, Rb + n, kk, l), vwf + off);
        }
        #pragma unroll
        for (int fl = 0; fl < 2; ++fl){
          #pragma unroll
          for (int m = 0; m < 2; ++m)
            ak[hl][m][fl] = mfma16(WA[m], XF[fl], ak[hl][m][fl]);
          #pragma unroll
          for (int n = 0; n < 2; ++n)
            av[hl][fl][n] = mfma16(XF[fl], WB2[n], av[hl][fl][n]);
        }
      }
    }
    #pragma unroll
    for (int hl = 0; hl < 2; ++hl){
      const int cb = w*64 + hl*32;
      #pragma unroll
      for (int m = 0; m < 2; ++m){
        f32x4 bias = *(const f32x4*)(kb + cb + 16*m + 4*g);
        #pragma unroll
        for (int fl = 0; fl < 2; ++fl){
          f32x4 v;
          #pragma unroll
          for (int r = 0; r < 4; ++r) v[r] = ak[hl][m][fl][r] + bias[r];
          akpk[hl][m*4+2+fl] = pkfrag(v);
        }
      }
      #pragma unroll
      for (int n = 0; n < 2; ++n){
        float bias = vb[cb + 16*n + lo];
        #pragma unroll
        for (int fl = 0; fl < 2; ++fl){
          f32x4 v;
          #pragma unroll
          for (int r = 0; r < 4; ++r) v[r] = av[hl][fl][n][r] + bias;
          avpk[hl][(2+fl)*2+n] = pkfrag(v);
        }
      }
    }
  }

  // ---- P4: attention per head (registers only) + residual into r1 ----
  #pragma unroll
  for (int hl = 0; hl < 2; ++hl){
    const int cb = w*64 + hl*32;
    f32x4 y1h[2][4] = {};   // [md][n]
    #pragma unroll
    for (int n = 0; n < 4; ++n){
      f32x4 s4[4];
      #pragma unroll
      for (int f = 0; f < 4; ++f){
        f32x4 acc = {};
        acc = mfma1616(akpk[hl][0*4+f], aqpk[hl][0*4+n], acc);
        acc = mfma1616(akpk[hl][1*4+f], aqpk[hl][1*4+n], acc);
        s4[f] = acc;
      }
      float mx = s4[0][0];
      #pragma unroll
      for (int f = 0; f < 4; ++f)
        #pragma unroll
        for (int r = 0; r < 4; ++r)
          mx = fmaxf(mx, s4[f][r]);
      mx = fmaxf(mx, __shfl_xor(mx, 16));
      mx = fmaxf(mx, __shfl_xor(mx, 32));
      float sum = 0.f;
      #pragma unroll
      for (int f = 0; f < 4; ++f)
        #pragma unroll
        for (int r = 0; r < 4; ++r){
          float e = __expf(s4[f][r] - mx);
          s4[f][r] = e; sum += e;
        }
      sum += __shfl_xor(sum, 16);
      sum += __shfl_xor(sum, 32);
      float rin = 1.0f / (sum + 1.0f);
      u32x2 spk[4];
      #pragma unroll
      for (int f = 0; f < 4; ++f){
        f32x4 v;
        #pragma unroll
        for (int r = 0; r < 4; ++r) v[r] = s4[f][r] * rin;
        spk[f] = pkfrag(v);
      }
      #pragma unroll
      for (int md = 0; md < 2; ++md)
        #pragma unroll
        for (int f = 0; f < 4; ++f)
          y1h[md][n] = mfma1616(avpk[hl][f*2+md], spk[f], y1h[md][n]);
    }

    // residual: r1 += y1 (wave-private cols; all waves are past the P2 barrier,
    // so no wave is still reading r1 as Y)
    #pragma unroll
    for (int md = 0; md < 2; ++md)
      #pragma unroll
      for (int n = 0; n < 4; ++n){
        int c0 = cb + 16*md + 4*g;
        char* p = r1 + (16*n+lo)*512 + ((u32)(c0*2) ^ swr);
        u32x2 old = *(const u32x2*)p;
        f32x4 a = y1h[md][n];
        float o0 = bfl(old[0] & 0xffffu) + a[0];
        float o1 = bfl(old[0] >> 16)     + a[1];
        float o2 = bfl(old[1] & 0xffffu) + a[2];
        float o3 = bfl(old[1] >> 16)     + a[3];
        u32x2 nw; nw[0] = pk2(o0, o1); nw[1] = pk2(o2, o3);
        *(u32x2*)p = nw;
      }
  }
  __syncthreads();   // residual writes visible to all

  // ---- P5: proj: out = r1 @ proj_w^T + proj_b ----
  f32x4 ap[4][4] = {};
  #pragma unroll
  for (int kk = 0; kk < 8; ++kk){
    bf16x8 Af[4], Bp[4];
    #pragma unroll
    for (int m = 0; m < 4; ++m)
      Af[m] = ld16(r1 + (16*m+lo)*512 + ((u32)(kk*64 + 16*g) ^ swr));
    #pragma unroll
    for (int n = 0; n < 4; ++n){
      int off = (w*64 + 16*n + lo)*256 + kk*32 + 8*g;
      Bp[n] = loadw<BW>(wfrag(wb, 3, w*4 + n, kk, l), pwf + off);
    }
    #pragma unroll
    for (int m = 0; m < 4; ++m)
      #pragma unroll
      for (int n = 0; n < 4; ++n)
        ap[m][n] = mfma16(Af[m], Bp[n], ap[m][n]);
  }

  float pbv[4];
  #pragma unroll
  for (int n = 0; n < 4; ++n) pbv[n] = pb[w*64 + 16*n + lo];
  #pragma unroll
  for (int m = 0; m < 4; ++m)
    #pragma unroll
    for (int n = 0; n < 4; ++n)
      #pragma unroll
      for (int r = 0; r < 4; ++r)
        ap[m][n][r] += pbv[n];

  // ---- coalesced store via LDS transpose (r1 reused as [32][256] f32) ----
  float* ob = out + (size_t)b * 16384;
  #pragma unroll
  for (int half = 0; half < 2; ++half){
    __syncthreads();
    #pragma unroll
    for (int mm = 0; mm < 2; ++mm)
      #pragma unroll
      for (int n = 0; n < 4; ++n){
        int col = w*64 + 16*n + lo;
        #pragma unroll
        for (int r = 0; r < 4; ++r){
          int row = mm*16 + 4*g + r;                      // 0..31
          u32 byteoff = ((u32)(row*1024 + col*4)) ^ ((u32)(row & 4) << 4);
          *(float*)(r1 + byteoff) = ap[half*2 + mm][n][r];
        }
      }
    __syncthreads();
    #pragma unroll
    for (int i = 0; i < 8; ++i){
      int id  = i*256 + t;
      int row = id >> 6;                                  // 0..31
      int cc  = id & 63;
      u32 byteoff = (u32)(row*1024) + ((u32)(cc ^ (row & 4)) << 4);
      f32x4 v = *(const f32x4*)(r1 + byteoff);
      *(f32x4*)(ob + (half*32 + row)*256 + cc*4) = v;
    }
  }
}

extern "C" void kernel_launch(void* const* d_in, const int* in_sizes, int n_in,
                              void* d_out, int out_size, void* d_ws, size_t ws_size,
                              hipStream_t stream) {
  (void)n_in; (void)out_size;
  const float* x  = (const float*)d_in[0];
  const float* y  = (const float*)d_in[1];
  // d_in[2] (z) is unused by the reference forward
  const float* qw = (const float*)d_in[3];
  const float* qb = (const float*)d_in[4];
  const float* kw = (const float*)d_in[5];
  const float* kb = (const float*)d_in[6];
  const float* vw = (const float*)d_in[7];
  const float* vb = (const float*)d_in[8];
  const float* pw = (const float*)d_in[9];
  const float* pb = (const float*)d_in[10];
  float* out = (float*)d_out;
  const int Bn = in_sizes[0] / 16384;   // 2048

  const bool useWs = ws_size >= (size_t)524288;
  if (useWs){
    u16* wsb = (u16*)d_ws;
    prep_w<<<512, 64, 0, stream>>>(qw, kw, vw, pw, wsb);
    (void)hipFuncSetAttribute(reinterpret_cast<const void*>(&fused_ca<true>),
                              hipFuncAttributeMaxDynamicSharedMemorySize, 49152);
    fused_ca<true><<<Bn, 256, 49152, stream>>>(x, y, wsb, qw, kw, vw, pw,
                                               qb, kb, vb, pb, out);
  } else {
    (void)hipFuncSetAttribute(reinterpret_cast<const void*>(&fused_ca<false>),
                              hipFuncAttributeMaxDynamicSharedMemorySize, 49152);
    fused_ca<false><<<Bn, 256, 49152, stream>>>(x, y, (const u16*)d_ws, qw, kw, vw, pw,
                                                qb, kb, vb, pb, out);
  }
}

// Round 9
// 173.506 us; speedup vs baseline: 2.4507x; 1.0926x over previous
//
#include <hip/hip_runtime.h>

typedef __bf16 bf16x8 __attribute__((ext_vector_type(8)));
typedef __bf16 bf16x4 __attribute__((ext_vector_type(4)));
typedef short  s16x4  __attribute__((ext_vector_type(4)));
typedef float  f32x4  __attribute__((ext_vector_type(4)));
typedef unsigned int u32x4 __attribute__((ext_vector_type(4)));
typedef unsigned int u32x2 __attribute__((ext_vector_type(2)));
typedef unsigned int u32;
typedef unsigned short u16;

#define DEVI static __device__ __forceinline__

// Bn=2048, L=64, C=256, NH=8, HD=32
static constexpr float KSCALE = 0.17677669529663687f;  // 32^-0.5

DEVI u32 pk2(float a, float b){
  u16 ha = __builtin_bit_cast(u16, (__bf16)a);
  u16 hb = __builtin_bit_cast(u16, (__bf16)b);
  return (u32)ha | ((u32)hb << 16);
}
DEVI float bfl(u32 bits16){            // low 16 bits hold a bf16
  union { u32 i; float f; } v; v.i = bits16 << 16; return v.f;
}
DEVI u32x2 pkfrag(f32x4 v){ u32x2 o; o[0]=pk2(v[0],v[1]); o[1]=pk2(v[2],v[3]); return o; }
DEVI bf16x8 ld16(const void* p){ return __builtin_bit_cast(bf16x8, *(const u32x4*)p); }
DEVI f32x4 mfma16(bf16x8 a, bf16x8 b, f32x4 c){
  return __builtin_amdgcn_mfma_f32_16x16x32_bf16(a, b, c, 0, 0, 0);
}
// 16x16x16 bf16 MFMA: A/B frag layout is the transpose of the C/D layout ->
// S and PV consume Q/K/V/P straight from accumulator registers.
DEVI f32x4 mfma1616(u32x2 a, u32x2 b, f32x4 c){
#if __has_builtin(__builtin_amdgcn_mfma_f32_16x16x16_bf16)
  return __builtin_amdgcn_mfma_f32_16x16x16_bf16(
      __builtin_bit_cast(bf16x4, a), __builtin_bit_cast(bf16x4, b), c, 0, 0, 0);
#elif __has_builtin(__builtin_amdgcn_mfma_f32_16x16x16bf16_1k)
  return __builtin_amdgcn_mfma_f32_16x16x16bf16_1k(
      __builtin_bit_cast(s16x4, a), __builtin_bit_cast(s16x4, b), c, 0, 0, 0);
#else
  asm("v_mfma_f32_16x16x16_bf16 %0, %1, %2, %0" : "+v"(c) : "v"(a), "v"(b));
  return c;
#endif
}

template<bool BW>
DEVI bf16x8 loadw(const u16* wbp, const float* wfp){
  if constexpr (BW){
    return ld16(wbp);
  } else {
    f32x4 a = *(const f32x4*)wfp;
    f32x4 b = *(const f32x4*)(wfp + 4);
    u32x4 pc; pc[0]=pk2(a[0],a[1]); pc[1]=pk2(a[2],a[3]); pc[2]=pk2(b[0],b[1]); pc[3]=pk2(b[2],b[3]);
    return __builtin_bit_cast(bf16x8, pc);
  }
}

// Permuted weight layout: frag block (M, R, kk) is 1KB contiguous, lane-major:
//   dst[(((M*16+R)*8+kk)*64 + l)*8 + e] = W_M[R*16 + (l&15)][kk*32 + (l>>4)*8 + e]
__global__ void prep_w(const float* __restrict__ qw, const float* __restrict__ kw,
                       const float* __restrict__ vw, const float* __restrict__ pw,
                       u16* __restrict__ dst){
  int blk = blockIdx.x;            // 512 blocks: M(2b) R(4b) kk(3b)
  int l   = threadIdx.x;           // 64
  int M = blk >> 7, R = (blk >> 3) & 15, kk = blk & 7;
  const float* W = (M==0) ? qw : (M==1) ? kw : (M==2) ? vw : pw;
  const float* src = W + (R*16 + (l&15))*256 + kk*32 + (l>>4)*8;
  f32x4 a  = *(const f32x4*)src;
  f32x4 b2 = *(const f32x4*)(src + 4);
  u32x4 pc; pc[0]=pk2(a[0],a[1]); pc[1]=pk2(a[2],a[3]); pc[2]=pk2(b2[0],b2[1]); pc[3]=pk2(b2[2],b2[3]);
  *(u32x4*)(dst + (size_t)blk*512 + l*8) = pc;
}

DEVI const u16* wfrag(const u16* wb, int M, int R, int kk, int l){
  return wb + ((((M<<4) + R)<<3) + kk)*512 + l*8;
}

DEVI void stw(char* T, int idx, f32x4 v){   // pack f32x4 -> bf16x4, swizzled store
  int row = idx >> 6;
  int c0  = (idx & 63) * 4;
  u32x2 o; o[0] = pk2(v[0], v[1]); o[1] = pk2(v[2], v[3]);
  *(u32x2*)(T + row*512 + ((u32)(c0*2) ^ ((u32)(row&7) << 4))) = o;
}

// ---------------- Kernel 1: K/V projection, written as packed MFMA frags ----
// KV layout (u32x2 elements): [(b*8+head)*1024 + kv*512 + frag*64 + lane]
//   K frag index = m*4+f  (akpk order), V frag index = f*2+n (avpk order).
// Per batch item this occupies exactly the item's 64KB region of d_out;
// kernel 2 consumes it fully before overwriting with the final output.
template<bool BW>
__global__ __launch_bounds__(256, 2)
void prep_kv(const float* __restrict__ x, const u16* __restrict__ wb,
             const float* __restrict__ kwf, const float* __restrict__ vwf,
             const float* __restrict__ kb, const float* __restrict__ vb,
             u32x2* __restrict__ kvout)
{
  __shared__ char Xs[32768];
  const int b  = blockIdx.x;
  const int t  = threadIdx.x;
  const int w  = t >> 6;
  const int l  = t & 63;
  const int lo = l & 15;
  const int g  = l >> 4;
  const u32 swr = (u32)(lo & 7) << 4;
  const float* xb = x + (size_t)b * 16384;

  #pragma unroll
  for (int j = 0; j < 16; ++j){
    int idx = t + 256*j;
    f32x4 v = *(const f32x4*)(xb + (idx>>6)*256 + (idx&63)*4);
    stw(Xs, idx, v);
  }
  __syncthreads();

  #pragma unroll
  for (int hl = 0; hl < 2; ++hl){
    const int cb = w*64 + hl*32;
    const int Rb = w*4 + hl*2;
    f32x4 ak[2][4] = {};   // K^T tiles [m][f]
    f32x4 av[4][2] = {};   // V tiles [f][n]
    #pragma unroll
    for (int kk = 0; kk < 8; ++kk){
      bf16x8 WA[2], WB2[2], XF[4];
      #pragma unroll
      for (int m = 0; m < 2; ++m){
        int off = (cb + 16*m + lo)*256 + kk*32 + 8*g;
        WA[m] = loadw<BW>(wfrag(wb, 1, Rb + m, kk, l), kwf + off);
      }
      #pragma unroll
      for (int n = 0; n < 2; ++n){
        int off = (cb + 16*n + lo)*256 + kk*32 + 8*g;
        WB2[n] = loadw<BW>(wfrag(wb, 2, Rb + n, kk, l), vwf + off);
      }
      #pragma unroll
      for (int f = 0; f < 4; ++f)
        XF[f] = ld16(Xs + (16*f+lo)*512 + ((u32)(kk*64 + 16*g) ^ swr));
      #pragma unroll
      for (int f = 0; f < 4; ++f){
        #pragma unroll
        for (int m = 0; m < 2; ++m)
          ak[m][f] = mfma16(WA[m], XF[f], ak[m][f]);
        #pragma unroll
        for (int n = 0; n < 2; ++n)
          av[f][n] = mfma16(XF[f], WB2[n], av[f][n]);
      }
    }
    const size_t base = ((size_t)(b*8 + w*2 + hl)) * 1024;
    #pragma unroll
    for (int m = 0; m < 2; ++m){
      f32x4 bias = *(const f32x4*)(kb + cb + 16*m + 4*g);
      #pragma unroll
      for (int f = 0; f < 4; ++f){
        f32x4 v;
        #pragma unroll
        for (int r = 0; r < 4; ++r) v[r] = ak[m][f][r] + bias[r];
        kvout[base + (size_t)(m*4+f)*64 + l] = pkfrag(v);
      }
    }
    #pragma unroll
    for (int n = 0; n < 2; ++n){
      float bias = vb[cb + 16*n + lo];
      #pragma unroll
      for (int f = 0; f < 4; ++f){
        f32x4 v;
        #pragma unroll
        for (int r = 0; r < 4; ++r) v[r] = av[f][n][r] + bias;
        kvout[base + 512 + (size_t)(f*2+n)*64 + l] = pkfrag(v);
      }
    }
  }
}

// ---------------- Kernel 2: Q + attention + residual + proj ----------------
// One block per batch item. 256 threads = 4 waves; wave w owns heads {2w,2w+1}.
// LDS 32KB static: r1 = Y/(Y+Y1) bf16 [64][256] pitch 512B swizzled; epilogue
// reuses it as [32][256] f32. KV frags come straight from global (L3-warm),
// loaded per head to keep peak VGPR ~120. NOTE: kvin aliases out (d_out);
// all KV reads precede the epilogue stores (barrier-ordered) -- no __restrict__.
template<bool BW>
__global__ __launch_bounds__(256, 2)
void fused_att(const float* __restrict__ y, const u16* __restrict__ wb,
               const float* __restrict__ qwf, const float* __restrict__ pwf,
               const float* __restrict__ qb, const float* __restrict__ pb,
               const u32x2* kvin, float* out)
{
  __shared__ char r1[32768];
  const int b  = blockIdx.x;
  const int t  = threadIdx.x;
  const int w  = t >> 6;
  const int l  = t & 63;
  const int lo = l & 15;
  const int g  = l >> 4;
  const u32 swr = (u32)(lo & 7) << 4;
  const float* yb = y + (size_t)b * 16384;

  // ---- stage Y -> r1 (bf16, swizzled) ----
  #pragma unroll
  for (int j = 0; j < 16; ++j){
    int idx = t + 256*j;
    f32x4 v = *(const f32x4*)(yb + (idx>>6)*256 + (idx&63)*4);
    stw(r1, idx, v);
  }
  __syncthreads();   // Y readable

  // ---- Q-GEMMs (both heads) ----
  u32x2 aqpk[2][8];    // [hl][m*4+n]
  #pragma unroll
  for (int hl = 0; hl < 2; ++hl){
    const int cb = w*64 + hl*32;
    const int Rb = w*4 + hl*2;
    f32x4 aq[2][4] = {};
    #pragma unroll
    for (int kk = 0; kk < 8; ++kk){
      bf16x8 A[2], Bf[4];
      #pragma unroll
      for (int m = 0; m < 2; ++m){
        int off = (cb + 16*m + lo)*256 + kk*32 + 8*g;
        A[m] = loadw<BW>(wfrag(wb, 0, Rb + m, kk, l), qwf + off);
      }
      #pragma unroll
      for (int n = 0; n < 4; ++n)
        Bf[n] = ld16(r1 + (16*n+lo)*512 + ((u32)(kk*64 + 16*g) ^ swr));
      #pragma unroll
      for (int m = 0; m < 2; ++m)
        #pragma unroll
        for (int n = 0; n < 4; ++n)
          aq[m][n] = mfma16(A[m], Bf[n], aq[m][n]);
    }
    #pragma unroll
    for (int m = 0; m < 2; ++m){
      f32x4 bias = *(const f32x4*)(qb + cb + 16*m + 4*g);
      #pragma unroll
      for (int n = 0; n < 4; ++n){
        f32x4 v;
        #pragma unroll
        for (int r = 0; r < 4; ++r) v[r] = (aq[m][n][r] + bias[r]) * KSCALE;
        aqpk[hl][m*4+n] = pkfrag(v);
      }
    }
  }
  __syncthreads();   // all Q-GEMM reads of r1(Y) done; residual writes now safe

  // ---- per head: load KV frags, attention (registers only), residual ----
  #pragma unroll
  for (int hl = 0; hl < 2; ++hl){
    const int cb = w*64 + hl*32;
    const size_t base = ((size_t)(b*8 + w*2 + hl)) * 1024;
    u32x2 akpk[8], avpk[8];
    #pragma unroll
    for (int f = 0; f < 8; ++f) akpk[f] = kvin[base + (size_t)f*64 + l];
    #pragma unroll
    for (int f = 0; f < 8; ++f) avpk[f] = kvin[base + 512 + (size_t)f*64 + l];

    f32x4 y1h[2][4] = {};   // [md][n]
    #pragma unroll
    for (int n = 0; n < 4; ++n){
      f32x4 s4[4];
      #pragma unroll
      for (int f = 0; f < 4; ++f){
        f32x4 acc = {};
        acc = mfma1616(akpk[0*4+f], aqpk[hl][0*4+n], acc);
        acc = mfma1616(akpk[1*4+f], aqpk[hl][1*4+n], acc);
        s4[f] = acc;
      }
      float mx = s4[0][0];
      #pragma unroll
      for (int f = 0; f < 4; ++f)
        #pragma unroll
        for (int r = 0; r < 4; ++r)
          mx = fmaxf(mx, s4[f][r]);
      mx = fmaxf(mx, __shfl_xor(mx, 16));
      mx = fmaxf(mx, __shfl_xor(mx, 32));
      float sum = 0.f;
      #pragma unroll
      for (int f = 0; f < 4; ++f)
        #pragma unroll
        for (int r = 0; r < 4; ++r){
          float e = __expf(s4[f][r] - mx);
          s4[f][r] = e; sum += e;
        }
      sum += __shfl_xor(sum, 16);
      sum += __shfl_xor(sum, 32);
      float rin = 1.0f / (sum + 1.0f);
      u32x2 spk[4];
      #pragma unroll
      for (int f = 0; f < 4; ++f){
        f32x4 v;
        #pragma unroll
        for (int r = 0; r < 4; ++r) v[r] = s4[f][r] * rin;
        spk[f] = pkfrag(v);
      }
      #pragma unroll
      for (int md = 0; md < 2; ++md)
        #pragma unroll
        for (int f = 0; f < 4; ++f)
          y1h[md][n] = mfma1616(avpk[f*2+md], spk[f], y1h[md][n]);
    }

    // residual: r1 += y1 (wave-private cols)
    #pragma unroll
    for (int md = 0; md < 2; ++md)
      #pragma unroll
      for (int n = 0; n < 4; ++n){
        int c0 = cb + 16*md + 4*g;
        char* p = r1 + (16*n+lo)*512 + ((u32)(c0*2) ^ swr);
        u32x2 old = *(const u32x2*)p;
        f32x4 a = y1h[md][n];
        float o0 = bfl(old[0] & 0xffffu) + a[0];
        float o1 = bfl(old[0] >> 16)     + a[1];
        float o2 = bfl(old[1] & 0xffffu) + a[2];
        float o3 = bfl(old[1] >> 16)     + a[3];
        u32x2 nw; nw[0] = pk2(o0, o1); nw[1] = pk2(o2, o3);
        *(u32x2*)p = nw;
      }
  }
  __syncthreads();   // residual writes visible to all

  // ---- proj: out = r1 @ proj_w^T + proj_b ----
  f32x4 ap[4][4] = {};
  #pragma unroll
  for (int kk = 0; kk < 8; ++kk){
    bf16x8 Af[4], Bp[4];
    #pragma unroll
    for (int m = 0; m < 4; ++m)
      Af[m] = ld16(r1 + (16*m+lo)*512 + ((u32)(kk*64 + 16*g) ^ swr));
    #pragma unroll
    for (int n = 0; n < 4; ++n){
      int off = (w*64 + 16*n + lo)*256 + kk*32 + 8*g;
      Bp[n] = loadw<BW>(wfrag(wb, 3, w*4 + n, kk, l), pwf + off);
    }
    #pragma unroll
    for (int m = 0; m < 4; ++m)
      #pragma unroll
      for (int n = 0; n < 4; ++n)
        ap[m][n] = mfma16(Af[m], Bp[n], ap[m][n]);
  }

  float pbv[4];
  #pragma unroll
  for (int n = 0; n < 4; ++n) pbv[n] = pb[w*64 + 16*n + lo];
  #pragma unroll
  for (int m = 0; m < 4; ++m)
    #pragma unroll
    for (int n = 0; n < 4; ++n)
      #pragma unroll
      for (int r = 0; r < 4; ++r)
        ap[m][n][r] += pbv[n];

  // ---- coalesced store via LDS transpose (r1 reused as [32][256] f32) ----
  float* ob = out + (size_t)b * 16384;
  #pragma unroll
  for (int half = 0; half < 2; ++half){
    __syncthreads();
    #pragma unroll
    for (int mm = 0; mm < 2; ++mm)
      #pragma unroll
      for (int n = 0; n < 4; ++n){
        int col = w*64 + 16*n + lo;
        #pragma unroll
        for (int r = 0; r < 4; ++r){
          int row = mm*16 + 4*g + r;                      // 0..31
          u32 byteoff = ((u32)(row*1024 + col*4)) ^ ((u32)(row & 4) << 4);
          *(float*)(r1 + byteoff) = ap[half*2 + mm][n][r];
        }
      }
    __syncthreads();
    #pragma unroll
    for (int i = 0; i < 8; ++i){
      int id  = i*256 + t;
      int row = id >> 6;                                  // 0..31
      int cc  = id & 63;
      u32 byteoff = (u32)(row*1024) + ((u32)(cc ^ (row & 4)) << 4);
      f32x4 v = *(const f32x4*)(r1 + byteoff);
      *(f32x4*)(ob + (half*32 + row)*256 + cc*4) = v;
    }
  }
}

extern "C" void kernel_launch(void* const* d_in, const int* in_sizes, int n_in,
                              void* d_out, int out_size, void* d_ws, size_t ws_size,
                              hipStream_t stream) {
  (void)n_in; (void)out_size;
  const float* x  = (const float*)d_in[0];
  const float* y  = (const float*)d_in[1];
  // d_in[2] (z) is unused by the reference forward
  const float* qw = (const float*)d_in[3];
  const float* qb = (const float*)d_in[4];
  const float* kw = (const float*)d_in[5];
  const float* kb = (const float*)d_in[6];
  const float* vw = (const float*)d_in[7];
  const float* vb = (const float*)d_in[8];
  const float* pw = (const float*)d_in[9];
  const float* pb = (const float*)d_in[10];
  float* out = (float*)d_out;
  const int Bn = in_sizes[0] / 16384;   // 2048

  const bool useWs = ws_size >= (size_t)524288;
  if (useWs){
    u16* wsb = (u16*)d_ws;
    prep_w<<<512, 64, 0, stream>>>(qw, kw, vw, pw, wsb);
    prep_kv<true><<<Bn, 256, 0, stream>>>(x, wsb, kw, vw, kb, vb, (u32x2*)d_out);
    fused_att<true><<<Bn, 256, 0, stream>>>(y, wsb, qw, pw, qb, pb,
                                            (const u32x2*)d_out, out);
  } else {
    prep_kv<false><<<Bn, 256, 0, stream>>>(x, (const u16*)d_ws, kw, vw, kb, vb,
                                           (u32x2*)d_out);
    fused_att<false><<<Bn, 256, 0, stream>>>(y, (const u16*)d_ws, qw, pw, qb, pb,
                                             (const u32x2*)d_out, out);
  }
}